// Round 9
// baseline (684.215 us; speedup 1.0000x reference)
//
#include <hip/hip_runtime.h>
#include <math.h>

#define NN 10000
#define NE 320000
#define NODE_F 64
#define EDGE_F 32
#define HDIM 256
#define HEADS 8
#define LAYERS 6
#define NG 16
#define DCAP 128
#define NPB 2  // nodes per node_kernel block; 2 waves per node

typedef __attribute__((ext_vector_type(8))) short short8;
typedef __attribute__((ext_vector_type(4))) float float4v;

// ---------------------------------------------------------------- CSR build
__global__ void count_kernel(const int* __restrict__ dst, int* __restrict__ cnt) {
    int e = blockIdx.x * 256 + threadIdx.x;
    if (e < NE) atomicAdd(&cnt[dst[e]], 1);
}

__global__ void scan_kernel(const int* __restrict__ cnt, int* __restrict__ row_ptr,
                            int* __restrict__ pos) {
    __shared__ int part[1024];
    int t = threadIdx.x;
    const int chunk = (NN + 1023) / 1024;  // 10
    int lo = t * chunk, hi = min(NN, lo + chunk);
    int s = 0;
    for (int i = lo; i < hi; ++i) s += cnt[i];
    part[t] = s;
    __syncthreads();
    for (int off = 1; off < 1024; off <<= 1) {
        int v = (t >= off) ? part[t - off] : 0;
        __syncthreads();
        part[t] += v;
        __syncthreads();
    }
    int base = (t == 0) ? 0 : part[t - 1];
    for (int i = lo; i < hi; ++i) {
        row_ptr[i] = base;
        pos[i] = base;
        base += cnt[i];
    }
    if (t == 1023) row_ptr[NN] = part[1023];
}

// scatter + permute edge_attr into CSR order (128 B contiguous per edge:
// full-line-covered scatter writes, no HBM write amplification)
__global__ void scatter_kernel(const int* __restrict__ src, const int* __restrict__ dst,
                               const float* __restrict__ edge_attr,
                               int* __restrict__ pos, int* __restrict__ csr_src,
                               float* __restrict__ ea_csr) {
    int e = blockIdx.x * 256 + threadIdx.x;
    if (e >= NE) return;
    int d = dst[e];
    int idx = atomicAdd(&pos[d], 1);
    csr_src[idx] = src[e];
    const float4* p = (const float4*)(edge_attr + (size_t)e * EDGE_F);
    float4* q = (float4*)(ea_csr + (size_t)idx * EDGE_F);
    #pragma unroll
    for (int i = 0; i < 8; ++i) q[i] = p[i];
}

// ---------------------------------------------------------------- edge-attn weight folding
__global__ void v_kernel(const float* __restrict__ att_edge, const float* __restrict__ lin_edge_w,
                         float* __restrict__ v) {
    int idx = blockIdx.x * 256 + threadIdx.x;
    if (idx >= LAYERS * HEADS * HDIM) return;
    int i = idx / (HEADS * HDIM);
    int r = idx % (HEADS * HDIM);
    int h = r / HDIM, k = r % HDIM;
    float s = 0.f;
    #pragma unroll 4
    for (int o = 0; o < 32; ++o)
        s += att_edge[(i * HEADS + h) * 32 + o] *
             lin_edge_w[((size_t)i * HDIM + h * 32 + o) * HDIM + k];
    v[idx] = s;
}

__global__ void we_kernel(const float* __restrict__ v, const float* __restrict__ edge_emb_w,
                          const float* __restrict__ edge_emb_b, float* __restrict__ we,
                          float* __restrict__ be) {
    int idx = blockIdx.x * 256 + threadIdx.x;
    if (idx < LAYERS * HEADS * EDGE_F) {
        int i = idx / (HEADS * EDGE_F);
        int r = idx % (HEADS * EDGE_F);
        int h = r >> 5, f = r & 31;
        float s = 0.f;
        for (int k = 0; k < HDIM; ++k)
            s += v[(i * HEADS + h) * HDIM + k] * edge_emb_w[k * EDGE_F + f];
        we[idx] = s;
    } else if (idx < LAYERS * HEADS * EDGE_F + LAYERS * HEADS) {
        int j = idx - LAYERS * HEADS * EDGE_F;
        int i = j / HEADS, h = j % HEADS;
        float s = 0.f;
        for (int k = 0; k < HDIM; ++k) s += v[(i * HEADS + h) * HDIM + k] * edge_emb_b[k];
        be[j] = s;
    }
}

// ---------------------------------------------------------------- bf16 helpers
__device__ __forceinline__ ushort f2bf(float f) {
    union { float f; unsigned u; } v; v.f = f;
    unsigned u = v.u;
    return (ushort)((u + 0x7fffu + ((u >> 16) & 1u)) >> 16);
}
__device__ __forceinline__ float bf2f(ushort b) {
    union { unsigned u; float f; } v; v.u = ((unsigned)b) << 16; return v.f;
}

// ---------------------------------------------------------------- layer-invariant logit partials
// CSR-order: coalesced reads of ea_csr, coalesced writes of preEb.
__global__ __launch_bounds__(256) void preE_kernel(const float* __restrict__ ea_csr,
                                                   const float* __restrict__ we,
                                                   const float* __restrict__ be,
                                                   ushort* __restrict__ preEb) {
    __shared__ float swe[LAYERS * HEADS * EDGE_F];
    __shared__ float sbe[LAYERS * HEADS];
    int t = threadIdx.x;
    for (int i = t; i < LAYERS * HEADS * EDGE_F; i += 256) swe[i] = we[i];
    for (int i = t; i < LAYERS * HEADS; i += 256) sbe[i] = be[i];
    __syncthreads();
    int idx = blockIdx.x * 256 + t;
    if (idx >= NE) return;
    float ea[32];
    const float4* pp = (const float4*)(ea_csr + (size_t)idx * EDGE_F);
    #pragma unroll
    for (int q = 0; q < 8; ++q) {
        float4 v = pp[q];
        ea[q * 4] = v.x; ea[q * 4 + 1] = v.y; ea[q * 4 + 2] = v.z; ea[q * 4 + 3] = v.w;
    }
    for (int li = 0; li < LAYERS; ++li) {
        float out[8];
        #pragma unroll
        for (int h = 0; h < 8; ++h) {
            const float* wr = &swe[(li * HEADS + h) * EDGE_F];
            float s = sbe[li * HEADS + h];
            #pragma unroll
            for (int c = 0; c < 32; ++c) s += ea[c] * wr[c];
            out[h] = s;
        }
        uint4 pk;
        pk.x = (unsigned)f2bf(out[0]) | ((unsigned)f2bf(out[1]) << 16);
        pk.y = (unsigned)f2bf(out[2]) | ((unsigned)f2bf(out[3]) << 16);
        pk.z = (unsigned)f2bf(out[4]) | ((unsigned)f2bf(out[5]) << 16);
        pk.w = (unsigned)f2bf(out[6]) | ((unsigned)f2bf(out[7]) << 16);
        *(uint4*)(preEb + ((size_t)li * NE + idx) * 8) = pk;
    }
}

// preL[l][n][h] = deg>0 ? mean over CSR range of preE (contains folded bias) : 0
__global__ __launch_bounds__(256) void preL_kernel(const ushort* __restrict__ preEb,
                                                   const int* __restrict__ row_ptr,
                                                   float* __restrict__ preL) {
    int g = threadIdx.x >> 5, c = threadIdx.x & 31;
    int n = blockIdx.x * 8 + g;  // NN % 8 == 0
    int start = row_ptr[n], end = row_ptr[n + 1];
    int deg = end - start;
    for (int li = 0; li < LAYERS; ++li) {
        float s[8] = {};
        for (int idx = start + c; idx < end; idx += 32) {
            uint4 pk = *(const uint4*)(preEb + ((size_t)li * NE + idx) * 8);
            s[0] += bf2f((ushort)(pk.x & 0xffff)); s[1] += bf2f((ushort)(pk.x >> 16));
            s[2] += bf2f((ushort)(pk.y & 0xffff)); s[3] += bf2f((ushort)(pk.y >> 16));
            s[4] += bf2f((ushort)(pk.z & 0xffff)); s[5] += bf2f((ushort)(pk.z >> 16));
            s[6] += bf2f((ushort)(pk.w & 0xffff)); s[7] += bf2f((ushort)(pk.w >> 16));
        }
        #pragma unroll
        for (int off = 16; off >= 1; off >>= 1)
            #pragma unroll
            for (int h = 0; h < 8; ++h) s[h] += __shfl_xor(s[h], off, 32);
        if (c == 0) {
            float invd = deg > 0 ? 1.f / (float)deg : 0.f;
            float4* dstp = (float4*)(preL + ((size_t)li * NN + n) * 8);
            dstp[0] = make_float4(s[0] * invd, s[1] * invd, s[2] * invd, s[3] * invd);
            dstp[1] = make_float4(s[4] * invd, s[5] * invd, s[6] * invd, s[7] * invd);
        }
    }
}

// ---------------------------------------------------------------- splits
__global__ void split_kernel(const float* __restrict__ src, ushort* __restrict__ hi,
                             ushort* __restrict__ lo, int n) {
    int i = blockIdx.x * 256 + threadIdx.x;
    if (i >= n) return;
    float f = src[i];
    ushort h = f2bf(f);
    hi[i] = h;
    lo[i] = f2bf(f - bf2f(h));
}

__global__ void tobf_kernel(const float* __restrict__ src, ushort* __restrict__ dst, int n) {
    int i = blockIdx.x * 256 + threadIdx.x;
    if (i < n) dst[i] = f2bf(src[i]);
}

// ---------------------------------------------------------------- bf16x2 MFMA GEMM
__global__ __launch_bounds__(128) void gemm_bf2(const ushort* __restrict__ Ah,
                                                const ushort* __restrict__ Bh,
                                                const ushort* __restrict__ Bl,
                                                const float* __restrict__ bias,
                                                float* __restrict__ C,
                                                ushort* __restrict__ Chi,
                                                int N, int K, int J) {
    __shared__ ushort sAh[64][40], sBh[64][40], sBl[64][40];
    int nb = blockIdx.y * 64, jb = blockIdx.x * 64;
    int t = threadIdx.x, w = t >> 6, l = t & 63;
    int srow = t >> 1, sq = (t & 1) * 16;
    int fr = l & 15, fq = (l >> 4) * 8;
    float4v acc[2][4] = {};
    for (int kt = 0; kt < K; kt += 32) {
        int gr = nb + srow;
        short8 a0 = {0,0,0,0,0,0,0,0}, a1 = {0,0,0,0,0,0,0,0};
        if (gr < N) {
            const short8* pa = (const short8*)(Ah + (size_t)gr * K + kt + sq);
            a0 = pa[0]; a1 = pa[1];
        }
        *(short8*)&sAh[srow][sq] = a0; *(short8*)&sAh[srow][sq + 8] = a1;
        const short8* pb = (const short8*)(Bh + (size_t)(jb + srow) * K + kt + sq);
        short8 b0 = pb[0], b1 = pb[1];
        *(short8*)&sBh[srow][sq] = b0; *(short8*)&sBh[srow][sq + 8] = b1;
        const short8* pl = (const short8*)(Bl + (size_t)(jb + srow) * K + kt + sq);
        short8 l0 = pl[0], l1 = pl[1];
        *(short8*)&sBl[srow][sq] = l0; *(short8*)&sBl[srow][sq + 8] = l1;
        __syncthreads();
        short8 bh[4], bl[4];
        #pragma unroll
        for (int nt = 0; nt < 4; ++nt) {
            bh[nt] = *(const short8*)&sBh[nt * 16 + fr][fq];
            bl[nt] = *(const short8*)&sBl[nt * 16 + fr][fq];
        }
        #pragma unroll
        for (int mt = 0; mt < 2; ++mt) {
            short8 ah = *(const short8*)&sAh[w * 32 + mt * 16 + fr][fq];
            #pragma unroll
            for (int nt = 0; nt < 4; ++nt) {
                acc[mt][nt] = __builtin_amdgcn_mfma_f32_16x16x32_bf16(ah, bh[nt], acc[mt][nt], 0, 0, 0);
                acc[mt][nt] = __builtin_amdgcn_mfma_f32_16x16x32_bf16(ah, bl[nt], acc[mt][nt], 0, 0, 0);
            }
        }
        __syncthreads();
    }
    #pragma unroll
    for (int mt = 0; mt < 2; ++mt) {
        #pragma unroll
        for (int nt = 0; nt < 4; ++nt) {
            int col = jb + nt * 16 + fr;
            float bv = bias ? bias[col] : 0.f;
            #pragma unroll
            for (int r = 0; r < 4; ++r) {
                int row = nb + w * 32 + mt * 16 + (l >> 4) * 4 + r;
                if (row < N) {
                    float v = acc[mt][nt][r] + bv;
                    C[(size_t)row * J + col] = v;
                    if (Chi) Chi[(size_t)row * J + col] = f2bf(v);
                }
            }
        }
    }
}

// ---------------------------------------------------------------- per-node a_src/a_dst from bf16 xw
__global__ void asrcdst_kernel(const ushort* __restrict__ xwbf, const float* __restrict__ att_s,
                               const float* __restrict__ att_d, float* __restrict__ a_src,
                               float* __restrict__ a_dst) {
    int tid = blockIdx.x * 256 + threadIdx.x;
    if (tid >= NN * HEADS) return;
    int n = tid >> 3, h = tid & 7;
    const uint4* xv = (const uint4*)(xwbf + (size_t)n * HDIM + h * 32);
    const float4* sv = (const float4*)(att_s + h * 32);
    const float4* dv = (const float4*)(att_d + h * 32);
    float s1 = 0.f, s2 = 0.f;
    #pragma unroll
    for (int q = 0; q < 4; ++q) {
        uint4 pk = xv[q];
        float xx[8] = {bf2f((ushort)(pk.x & 0xffff)), bf2f((ushort)(pk.x >> 16)),
                       bf2f((ushort)(pk.y & 0xffff)), bf2f((ushort)(pk.y >> 16)),
                       bf2f((ushort)(pk.z & 0xffff)), bf2f((ushort)(pk.z >> 16)),
                       bf2f((ushort)(pk.w & 0xffff)), bf2f((ushort)(pk.w >> 16))};
        float4 a0 = sv[q * 2], a1 = sv[q * 2 + 1];
        float4 b0 = dv[q * 2], b1 = dv[q * 2 + 1];
        s1 += xx[0] * a0.x + xx[1] * a0.y + xx[2] * a0.z + xx[3] * a0.w
            + xx[4] * a1.x + xx[5] * a1.y + xx[6] * a1.z + xx[7] * a1.w;
        s2 += xx[0] * b0.x + xx[1] * b0.y + xx[2] * b0.z + xx[3] * b0.w
            + xx[4] * b1.x + xx[5] * b1.y + xx[6] * b1.z + xx[7] * b1.w;
    }
    a_src[tid] = s1;
    a_dst[tid] = s2;
}

__device__ __forceinline__ float gelu_exact(float x) {
    return 0.5f * x * (1.f + erff(x * 0.70710678118654752f));
}

// softmax without max-subtraction (shift-invariant; logits O(1), clamp guards overflow)
__device__ __forceinline__ float edge_wt_recompute(int idx, int sn, int hc, float adnh,
                                                   const ushort* __restrict__ preEb,
                                                   const float* __restrict__ a_src) {
    float a = a_src[(size_t)sn * 8 + hc] + adnh + bf2f(preEb[(size_t)idx * 8 + hc]);
    a = a > 0.f ? a : 0.2f * a;
    return expf(fminf(a, 40.f));
}

// ---------------------------------------------------------------- fused alpha + softmax + aggregate + LN + GELU + residual
// 2 nodes/block, 2 waves/node. Pass 1: 128 lanes stride the edge range.
// Pass 2: each wave aggregates half the range; partials combined via LDS.
__global__ __launch_bounds__(256) void node_kernel(const float* __restrict__ xw,
                                                  const ushort* __restrict__ xwbf,
                                                  const ushort* __restrict__ preEb,
                                                  const float* __restrict__ preL,
                                                  const float* __restrict__ a_src,
                                                  const float* __restrict__ a_dst,
                                                  const int* __restrict__ row_ptr,
                                                  const int* __restrict__ csr_src,
                                                  const float* __restrict__ h_prev,
                                                  float* __restrict__ h_next,
                                                  ushort* __restrict__ hhi,
                                                  const float* __restrict__ cb,
                                                  const float* __restrict__ lg,
                                                  const float* __restrict__ lb, int first) {
    __shared__ float lwAll[NPB][DCAP][9];
    __shared__ float sden[NPB][2][8];
    __shared__ float accx[NPB][64][4];
    int t = threadIdx.x;
    int wn = t >> 7;          // node within block
    int wp = (t >> 6) & 1;    // wave within pair
    int l = t & 63;           // lane within wave
    int tp = t & 127;         // lane within pair
    int n = blockIdx.x * NPB + wn;
    float (*lw)[9] = lwAll[wn];
    int start = row_ptr[n], end = row_ptr[n + 1];

    float adn[8], wl[8], sp[8];
    #pragma unroll
    for (int h = 0; h < 8; ++h) adn[h] = a_dst[n * 8 + h];
    #pragma unroll
    for (int h = 0; h < 8; ++h) {
        float al = a_src[n * 8 + h] + adn[h] + preL[n * 8 + h];
        al = al > 0.f ? al : 0.2f * al;
        wl[h] = expf(fminf(al, 40.f));
        sp[h] = (tp == 0) ? wl[h] : 0.f;
    }
    // pass 1: logits -> exp -> LDS cache + partial denom (128-lane stride)
    for (int idx = start + tp; idx < end; idx += 128) {
        int sn = csr_src[idx];
        uint4 pk = *(const uint4*)(preEb + (size_t)idx * 8);
        float p[8] = {bf2f((ushort)(pk.x & 0xffff)), bf2f((ushort)(pk.x >> 16)),
                      bf2f((ushort)(pk.y & 0xffff)), bf2f((ushort)(pk.y >> 16)),
                      bf2f((ushort)(pk.z & 0xffff)), bf2f((ushort)(pk.z >> 16)),
                      bf2f((ushort)(pk.w & 0xffff)), bf2f((ushort)(pk.w >> 16))};
        float4 s0 = *(const float4*)(a_src + (size_t)sn * 8);
        float4 s1 = *(const float4*)(a_src + (size_t)sn * 8 + 4);
        float al[8] = {s0.x + adn[0] + p[0], s0.y + adn[1] + p[1],
                       s0.z + adn[2] + p[2], s0.w + adn[3] + p[3],
                       s1.x + adn[4] + p[4], s1.y + adn[5] + p[5],
                       s1.z + adn[6] + p[6], s1.w + adn[7] + p[7]};
        int o = idx - start;
        #pragma unroll
        for (int h = 0; h < 8; ++h) {
            float a = al[h] > 0.f ? al[h] : 0.2f * al[h];
            float w = expf(fminf(a, 40.f));
            if (o < DCAP) lw[o][h] = w;
            sp[h] += w;
        }
    }
    #pragma unroll
    for (int off = 32; off >= 1; off >>= 1)
        #pragma unroll
        for (int h = 0; h < 8; ++h) sp[h] += __shfl_xor(sp[h], off, 64);
    if (l == 0) {
        #pragma unroll
        for (int h = 0; h < 8; ++h) sden[wn][wp][h] = sp[h];
    }
    __syncthreads();  // lw + sden visible
    float inv[8];
    #pragma unroll
    for (int h = 0; h < 8; ++h) inv[h] = 1.f / (sden[wn][0][h] + sden[wn][1][h] + 1e-16f);

    // pass 2: each wave aggregates half the edge range; lane owns channels 4l..4l+3
    int deg = end - start;
    int mid = start + ((deg + 1) >> 1);
    int b0 = wp ? mid : start;
    int b1 = wp ? end : mid;
    int hc = l >> 3;
    float adnh = adn[hc];
    const ushort* xb = xwbf + 4 * l;
    float acc[4] = {};
    if (wp == 0) {
        float4 xs = *(const float4*)(xw + (size_t)n * HDIM + 4 * l);
        float wself = wl[hc];
        acc[0] = wself * xs.x; acc[1] = wself * xs.y;
        acc[2] = wself * xs.z; acc[3] = wself * xs.w;
    }
    int idx = b0;
    for (; idx + 4 <= b1; idx += 4) {
        int o = idx - start;
        int sn0 = csr_src[idx + 0], sn1 = csr_src[idx + 1];
        int sn2 = csr_src[idx + 2], sn3 = csr_src[idx + 3];
        uint2 g0 = *(const uint2*)(xb + (size_t)sn0 * HDIM);
        uint2 g1 = *(const uint2*)(xb + (size_t)sn1 * HDIM);
        uint2 g2 = *(const uint2*)(xb + (size_t)sn2 * HDIM);
        uint2 g3 = *(const uint2*)(xb + (size_t)sn3 * HDIM);
        float w0, w1, w2, w3;
        if (o + 4 <= DCAP) {
            w0 = lw[o][hc]; w1 = lw[o + 1][hc]; w2 = lw[o + 2][hc]; w3 = lw[o + 3][hc];
        } else {
            w0 = (o + 0 < DCAP) ? lw[o + 0][hc] : edge_wt_recompute(idx + 0, sn0, hc, adnh, preEb, a_src);
            w1 = (o + 1 < DCAP) ? lw[o + 1][hc] : edge_wt_recompute(idx + 1, sn1, hc, adnh, preEb, a_src);
            w2 = (o + 2 < DCAP) ? lw[o + 2][hc] : edge_wt_recompute(idx + 2, sn2, hc, adnh, preEb, a_src);
            w3 = (o + 3 < DCAP) ? lw[o + 3][hc] : edge_wt_recompute(idx + 3, sn3, hc, adnh, preEb, a_src);
        }
        acc[0] += w0 * bf2f((ushort)(g0.x & 0xffff)) + w1 * bf2f((ushort)(g1.x & 0xffff))
                + w2 * bf2f((ushort)(g2.x & 0xffff)) + w3 * bf2f((ushort)(g3.x & 0xffff));
        acc[1] += w0 * bf2f((ushort)(g0.x >> 16)) + w1 * bf2f((ushort)(g1.x >> 16))
                + w2 * bf2f((ushort)(g2.x >> 16)) + w3 * bf2f((ushort)(g3.x >> 16));
        acc[2] += w0 * bf2f((ushort)(g0.y & 0xffff)) + w1 * bf2f((ushort)(g1.y & 0xffff))
                + w2 * bf2f((ushort)(g2.y & 0xffff)) + w3 * bf2f((ushort)(g3.y & 0xffff));
        acc[3] += w0 * bf2f((ushort)(g0.y >> 16)) + w1 * bf2f((ushort)(g1.y >> 16))
                + w2 * bf2f((ushort)(g2.y >> 16)) + w3 * bf2f((ushort)(g3.y >> 16));
    }
    for (; idx < b1; ++idx) {
        int o = idx - start;
        int sn = csr_src[idx];
        uint2 g = *(const uint2*)(xb + (size_t)sn * HDIM);
        float wt = (o < DCAP) ? lw[o][hc] : edge_wt_recompute(idx, sn, hc, adnh, preEb, a_src);
        acc[0] += wt * bf2f((ushort)(g.x & 0xffff));
        acc[1] += wt * bf2f((ushort)(g.x >> 16));
        acc[2] += wt * bf2f((ushort)(g.y & 0xffff));
        acc[3] += wt * bf2f((ushort)(g.y >> 16));
    }
    if (wp == 1) *(float4*)&accx[wn][l][0] = make_float4(acc[0], acc[1], acc[2], acc[3]);
    __syncthreads();
    if (wp == 1) return;  // no barriers below
    float4 ax = *(const float4*)&accx[wn][l][0];
    acc[0] += ax.x; acc[1] += ax.y; acc[2] += ax.z; acc[3] += ax.w;

    float4 cb4 = *(const float4*)(cb + 4 * l);
    float invh = inv[hc];
    acc[0] = acc[0] * invh + cb4.x;
    acc[1] = acc[1] * invh + cb4.y;
    acc[2] = acc[2] * invh + cb4.z;
    acc[3] = acc[3] * invh + cb4.w;

    // LayerNorm over 256 channels (single wave)
    float part = acc[0] + acc[1] + acc[2] + acc[3];
    #pragma unroll
    for (int off = 32; off >= 1; off >>= 1) part += __shfl_xor(part, off, 64);
    float mu = part * (1.f / 256.f);
    float p2 = 0.f;
    #pragma unroll
    for (int j = 0; j < 4; ++j) {
        float d = acc[j] - mu;
        p2 += d * d;
    }
    #pragma unroll
    for (int off = 32; off >= 1; off >>= 1) p2 += __shfl_xor(p2, off, 64);
    float rstd = rsqrtf(p2 * (1.f / 256.f) + 1e-5f);

    float4 lg4 = *(const float4*)(lg + 4 * l);
    float4 lb4 = *(const float4*)(lb + 4 * l);
    float o4[4];
    float lgv[4] = {lg4.x, lg4.y, lg4.z, lg4.w};
    float lbv[4] = {lb4.x, lb4.y, lb4.z, lb4.w};
    float4 hp = make_float4(0.f, 0.f, 0.f, 0.f);
    if (!first) hp = *(const float4*)(h_prev + (size_t)n * HDIM + 4 * l);
    float hpv[4] = {hp.x, hp.y, hp.z, hp.w};
    #pragma unroll
    for (int j = 0; j < 4; ++j) {
        float y = (acc[j] - mu) * rstd * lgv[j] + lbv[j];
        o4[j] = gelu_exact(y) + hpv[j];
    }
    *(float4*)(h_next + (size_t)n * HDIM + 4 * l) = make_float4(o4[0], o4[1], o4[2], o4[3]);
    uint2 ph;
    ph.x = (unsigned)f2bf(o4[0]) | ((unsigned)f2bf(o4[1]) << 16);
    ph.y = (unsigned)f2bf(o4[2]) | ((unsigned)f2bf(o4[3]) << 16);
    *(uint2*)(hhi + (size_t)n * HDIM + 4 * l) = ph;
}

// ---------------------------------------------------------------- graph readout
__global__ __launch_bounds__(256) void graph_sum_kernel(const float* __restrict__ h,
                                                        const int* __restrict__ batch,
                                                        float* __restrict__ sums) {
    int t = threadIdx.x;
    int n0 = blockIdx.x * 64;
    int n1 = min(NN, n0 + 64);
    float acc = 0.f;
    int cur = batch[n0];
    for (int n = n0; n < n1; ++n) {
        int b = batch[n];
        if (b != cur) {
            atomicAdd(&sums[cur * HDIM + t], acc);
            acc = 0.f;
            cur = b;
        }
        acc += h[(size_t)n * HDIM + t];
    }
    atomicAdd(&sums[cur * HDIM + t], acc);
}

__device__ __forceinline__ int lower_bound_dev(const int* a, int n, int v) {
    int lo = 0, hi = n;
    while (lo < hi) {
        int mid = (lo + hi) >> 1;
        if (a[mid] < v) lo = mid + 1; else hi = mid;
    }
    return lo;
}

// layer 1 of both MLP heads: grid (8, NG, 2)
__global__ __launch_bounds__(256) void mlp1_kernel(const float* __restrict__ sums,
                                                   const int* __restrict__ batch,
                                                   const float* __restrict__ pw1,
                                                   const float* __restrict__ pb1,
                                                   const float* __restrict__ mw1,
                                                   const float* __restrict__ mb1,
                                                   float* __restrict__ h1buf) {
    int slice = blockIdx.x, g = blockIdx.y, which = blockIdx.z;
    const float* w1 = which ? mw1 : pw1;
    const float* b1 = which ? mb1 : pb1;
    __shared__ float xg[512];
    __shared__ float cinv;
    int t = threadIdx.x;
    if (t == 0) {
        int s0 = lower_bound_dev(batch, NN, g), s1 = lower_bound_dev(batch, NN, g + 1);
        cinv = 1.f / fmaxf((float)(s1 - s0), 1.f);
    }
    __syncthreads();
    float sv = sums[g * HDIM + t];
    xg[t] = sv * cinv;
    xg[256 + t] = sv;
    __syncthreads();
    int row = slice * 32 + (t >> 3), lane8 = t & 7;
    const float* wr = w1 + (size_t)row * 512;
    float acc = 0.f;
    #pragma unroll
    for (int j = 0; j < 16; ++j) {
        int k = lane8 * 4 + j * 32;
        float4 wv = *(const float4*)(wr + k);
        acc += wv.x * xg[k] + wv.y * xg[k + 1] + wv.z * xg[k + 2] + wv.w * xg[k + 3];
    }
    #pragma unroll
    for (int off = 4; off >= 1; off >>= 1) acc += __shfl_xor(acc, off, 8);
    if (lane8 == 0) h1buf[((size_t)which * NG + g) * 256 + row] = gelu_exact(acc + b1[row]);
}

// layer 2: grid (4, NG, 2)
__global__ __launch_bounds__(256) void mlp2_kernel(const float* __restrict__ h1buf,
                                                   const float* __restrict__ pw2,
                                                   const float* __restrict__ pb2,
                                                   const float* __restrict__ mw2,
                                                   const float* __restrict__ mb2,
                                                   float* __restrict__ h2buf) {
    int slice = blockIdx.x, g = blockIdx.y, which = blockIdx.z;
    const float* w2 = which ? mw2 : pw2;
    const float* b2 = which ? mb2 : pb2;
    __shared__ float hx[256];
    int t = threadIdx.x;
    hx[t] = h1buf[((size_t)which * NG + g) * 256 + t];
    __syncthreads();
    int row = slice * 32 + (t >> 3), lane8 = t & 7;
    const float* wr = w2 + (size_t)row * 256;
    float acc = 0.f;
    #pragma unroll
    for (int j = 0; j < 8; ++j) {
        int k = lane8 * 4 + j * 32;
        float4 wv = *(const float4*)(wr + k);
        acc += wv.x * hx[k] + wv.y * hx[k + 1] + wv.z * hx[k + 2] + wv.w * hx[k + 3];
    }
    #pragma unroll
    for (int off = 4; off >= 1; off >>= 1) acc += __shfl_xor(acc, off, 8);
    if (lane8 == 0) h2buf[((size_t)which * NG + g) * 128 + row] = gelu_exact(acc + b2[row]);
}

// layer 3 + sigmoid: grid (NG, 2), 64 threads
__global__ __launch_bounds__(64) void mlp3_kernel(const float* __restrict__ h2buf,
                                                  const float* __restrict__ pw3,
                                                  const float* __restrict__ pb3,
                                                  const float* __restrict__ mw3,
                                                  const float* __restrict__ mb3,
                                                  float* __restrict__ out) {
    int g = blockIdx.x, which = blockIdx.y;
    const float* w3 = which ? mw3 : pw3;
    const float* b3 = which ? mb3 : pb3;
    int l = threadIdx.x;
    float v0 = h2buf[((size_t)which * NG + g) * 128 + l];
    float v1 = h2buf[((size_t)which * NG + g) * 128 + 64 + l];
    #pragma unroll
    for (int o = 0; o < 3; ++o) {
        float p = w3[o * 128 + l] * v0 + w3[o * 128 + 64 + l] * v1;
        #pragma unroll
        for (int off = 32; off >= 1; off >>= 1) p += __shfl_xor(p, off, 64);
        if (l == 0) out[which * (NG * 3) + g * 3 + o] = 1.f / (1.f + expf(-(p + b3[o])));
    }
}

// ---------------------------------------------------------------- launch
extern "C" void kernel_launch(void* const* d_in, const int* in_sizes, int n_in, void* d_out,
                              int out_size, void* d_ws, size_t ws_size, hipStream_t stream) {
    const float* x         = (const float*)d_in[0];
    const int*   ei        = (const int*)d_in[1];
    const int*   src       = ei;
    const int*   dst       = ei + NE;
    const float* edge_attr = (const float*)d_in[2];
    const int*   batch     = (const int*)d_in[3];
    const float* node_w    = (const float*)d_in[4];
    const float* node_b    = (const float*)d_in[5];
    const float* eew       = (const float*)d_in[6];
    const float* eeb       = (const float*)d_in[7];
    const float* lin_w     = (const float*)d_in[8];
    const float* att_src   = (const float*)d_in[9];
    const float* att_dst   = (const float*)d_in[10];
    const float* att_edge  = (const float*)d_in[11];
    const float* lin_edge_w= (const float*)d_in[12];
    const float* conv_b    = (const float*)d_in[13];
    const float* ln_g      = (const float*)d_in[14];
    const float* ln_b      = (const float*)d_in[15];
    const float* pw1 = (const float*)d_in[16]; const float* pb1 = (const float*)d_in[17];
    const float* pw2 = (const float*)d_in[18]; const float* pb2 = (const float*)d_in[19];
    const float* pw3 = (const float*)d_in[20]; const float* pb3 = (const float*)d_in[21];
    const float* mw1 = (const float*)d_in[22]; const float* mb1 = (const float*)d_in[23];
    const float* mw2 = (const float*)d_in[24]; const float* mb2 = (const float*)d_in[25];
    const float* mw3 = (const float*)d_in[26]; const float* mb3 = (const float*)d_in[27];
    float* out = (float*)d_out;

    float* wsf = (float*)d_ws;
    float* ea_csr    = wsf; wsf += (size_t)NE * EDGE_F;  // first: 128B-aligned rows
    float* hA        = wsf; wsf += (size_t)NN * HDIM;
    float* hB        = wsf; wsf += (size_t)NN * HDIM;
    float* xw        = wsf; wsf += (size_t)NN * HDIM;
    float* preL      = wsf; wsf += (size_t)LAYERS * NN * 8;
    float* a_src     = wsf; wsf += (size_t)NN * HEADS;
    float* a_dst     = wsf; wsf += (size_t)NN * HEADS;
    float* vbuf      = wsf; wsf += (size_t)LAYERS * HEADS * HDIM;
    float* webuf     = wsf; wsf += (size_t)LAYERS * HEADS * EDGE_F;
    float* bebuf     = wsf; wsf += 64;
    float* sums      = wsf; wsf += (size_t)NG * HDIM;
    float* h1buf     = wsf; wsf += (size_t)2 * NG * 256;
    float* h2buf     = wsf; wsf += (size_t)2 * NG * 128;
    ushort* ubuf = (ushort*)wsf;
    ushort* preEb = ubuf; ubuf += (size_t)LAYERS * NE * 8;
    ushort* hhi  = ubuf; ubuf += (size_t)NN * HDIM;
    ushort* xwbf = ubuf; ubuf += (size_t)NN * HDIM;
    ushort* wbhi = ubuf; ubuf += (size_t)LAYERS * HDIM * HDIM;
    ushort* wblo = ubuf; ubuf += (size_t)LAYERS * HDIM * HDIM;
    ushort* xhi  = ubuf; ubuf += (size_t)NN * NODE_F;
    ushort* nwhi = ubuf; ubuf += (size_t)HDIM * NODE_F;
    ushort* nwlo = ubuf; ubuf += (size_t)HDIM * NODE_F;
    int* ibuf    = (int*)ubuf;
    int* cnt     = ibuf; ibuf += NN + 16;
    int* row_ptr = ibuf; ibuf += NN + 16;
    int* pos     = ibuf; ibuf += NN + 16;
    int* csr_src = ibuf; ibuf += NE;

    // CSR build (+ permute edge_attr to CSR order)
    hipMemsetAsync(cnt, 0, NN * sizeof(int), stream);
    count_kernel<<<(NE + 255) / 256, 256, 0, stream>>>(dst, cnt);
    scan_kernel<<<1, 1024, 0, stream>>>(cnt, row_ptr, pos);
    scatter_kernel<<<(NE + 255) / 256, 256, 0, stream>>>(src, dst, edge_attr, pos, csr_src,
                                                         ea_csr);

    // fold edge-attention weights, hoist layer-invariant logit partials
    v_kernel<<<(LAYERS * HEADS * HDIM + 255) / 256, 256, 0, stream>>>(att_edge, lin_edge_w, vbuf);
    we_kernel<<<(LAYERS * HEADS * EDGE_F + LAYERS * HEADS + 255) / 256, 256, 0, stream>>>(
        vbuf, eew, eeb, webuf, bebuf);
    preE_kernel<<<(NE + 255) / 256, 256, 0, stream>>>(ea_csr, webuf, bebuf, preEb);
    preL_kernel<<<NN / 8, 256, 0, stream>>>(preEb, row_ptr, preL);

    // GEMM operand prep: weights hi+lo, activations bf16-hi only
    split_kernel<<<((LAYERS * HDIM * HDIM) + 255) / 256, 256, 0, stream>>>(lin_w, wbhi, wblo,
                                                                           LAYERS * HDIM * HDIM);
    split_kernel<<<((HDIM * NODE_F) + 255) / 256, 256, 0, stream>>>(node_w, nwhi, nwlo,
                                                                    HDIM * NODE_F);
    tobf_kernel<<<((NN * NODE_F) + 255) / 256, 256, 0, stream>>>(x, xhi, NN * NODE_F);

    // node embedding: hA = x @ node_w.T + node_b  (+ bf16 of hA)
    {
        dim3 grid(HDIM / 64, (NN + 63) / 64);
        gemm_bf2<<<grid, 128, 0, stream>>>(xhi, nwhi, nwlo, node_b, hA, hhi, NN, NODE_F, HDIM);
    }

    float* cur = hA;
    float* nxt = hB;
    for (int i = 0; i < LAYERS; ++i) {
        dim3 grid(HDIM / 64, (NN + 63) / 64);
        gemm_bf2<<<grid, 128, 0, stream>>>(hhi, wbhi + (size_t)i * HDIM * HDIM,
                                           wblo + (size_t)i * HDIM * HDIM, nullptr, xw,
                                           xwbf, NN, HDIM, HDIM);
        asrcdst_kernel<<<(NN * HEADS + 255) / 256, 256, 0, stream>>>(
            xwbf, att_src + i * HEADS * 32, att_dst + i * HEADS * 32, a_src, a_dst);
        node_kernel<<<NN / NPB, 256, 0, stream>>>(
            xw, xwbf, preEb + (size_t)i * NE * 8, preL + (size_t)i * NN * 8, a_src, a_dst,
            row_ptr, csr_src, cur, nxt, hhi, conv_b + i * HDIM, ln_g + i * HDIM,
            ln_b + i * HDIM, i == 0 ? 1 : 0);
        float* tmp = cur; cur = nxt; nxt = tmp;
    }

    hipMemsetAsync(sums, 0, NG * HDIM * sizeof(float), stream);
    graph_sum_kernel<<<(NN + 63) / 64, 256, 0, stream>>>(cur, batch, sums);
    {
        dim3 g1(8, NG, 2);
        mlp1_kernel<<<g1, 256, 0, stream>>>(sums, batch, pw1, pb1, mw1, mb1, h1buf);
        dim3 g2(4, NG, 2);
        mlp2_kernel<<<g2, 256, 0, stream>>>(h1buf, pw2, pb2, mw2, mb2, h2buf);
        dim3 g3(NG, 2);
        mlp3_kernel<<<g3, 64, 0, stream>>>(h2buf, pw3, pb3, mw3, mb3, out);
    }
}

// Round 10
// 615.428 us; speedup vs baseline: 1.1118x; 1.1118x over previous
//
#include <hip/hip_runtime.h>
#include <math.h>

#define NN 10000
#define NE 320000
#define NODE_F 64
#define EDGE_F 32
#define HDIM 256
#define HEADS 8
#define LAYERS 6
#define NG 16
#define DCAP 128
#define NPB 2   // nodes per node_kernel block, ONE wave per node (2-wave split regressed twice)
#define NOUT 48 // LAYERS*HEADS, interleaved preE layout [NE][48]

typedef __attribute__((ext_vector_type(8))) short short8;
typedef __attribute__((ext_vector_type(4))) float float4v;

// ---------------------------------------------------------------- CSR build
__global__ void count_kernel(const int* __restrict__ dst, int* __restrict__ cnt) {
    int e = blockIdx.x * 256 + threadIdx.x;
    if (e < NE) atomicAdd(&cnt[dst[e]], 1);
}

__global__ void scan_kernel(const int* __restrict__ cnt, int* __restrict__ row_ptr,
                            int* __restrict__ pos) {
    __shared__ int part[1024];
    int t = threadIdx.x;
    const int chunk = (NN + 1023) / 1024;  // 10
    int lo = t * chunk, hi = min(NN, lo + chunk);
    int s = 0;
    for (int i = lo; i < hi; ++i) s += cnt[i];
    part[t] = s;
    __syncthreads();
    for (int off = 1; off < 1024; off <<= 1) {
        int v = (t >= off) ? part[t - off] : 0;
        __syncthreads();
        part[t] += v;
        __syncthreads();
    }
    int base = (t == 0) ? 0 : part[t - 1];
    for (int i = lo; i < hi; ++i) {
        row_ptr[i] = base;
        pos[i] = base;
        base += cnt[i];
    }
    if (t == 1023) row_ptr[NN] = part[1023];
}

// ---------------------------------------------------------------- bf16 helpers
__device__ __forceinline__ ushort f2bf(float f) {
    union { float f; unsigned u; } v; v.f = f;
    unsigned u = v.u;
    return (ushort)((u + 0x7fffu + ((u >> 16) & 1u)) >> 16);
}
__device__ __forceinline__ float bf2f(ushort b) {
    union { unsigned u; float f; } v; v.u = ((unsigned)b) << 16; return v.f;
}

// scatter + permute edge_attr into CSR order as bf16 (64 B contiguous per edge)
__global__ void scatter_kernel(const int* __restrict__ src, const int* __restrict__ dst,
                               const float* __restrict__ edge_attr,
                               int* __restrict__ pos, int* __restrict__ csr_src,
                               ushort* __restrict__ ea_bf) {
    int e = blockIdx.x * 256 + threadIdx.x;
    if (e >= NE) return;
    int d = dst[e];
    int idx = atomicAdd(&pos[d], 1);
    csr_src[idx] = src[e];
    const float4* p = (const float4*)(edge_attr + (size_t)e * EDGE_F);
    uint4* q = (uint4*)(ea_bf + (size_t)idx * EDGE_F);
    #pragma unroll
    for (int i = 0; i < 4; ++i) {
        float4 v0 = p[i * 2], v1 = p[i * 2 + 1];
        uint4 pk;
        pk.x = (unsigned)f2bf(v0.x) | ((unsigned)f2bf(v0.y) << 16);
        pk.y = (unsigned)f2bf(v0.z) | ((unsigned)f2bf(v0.w) << 16);
        pk.z = (unsigned)f2bf(v1.x) | ((unsigned)f2bf(v1.y) << 16);
        pk.w = (unsigned)f2bf(v1.z) | ((unsigned)f2bf(v1.w) << 16);
        q[i] = pk;
    }
}

// ---------------------------------------------------------------- edge-attn weight folding
__global__ void v_kernel(const float* __restrict__ att_edge, const float* __restrict__ lin_edge_w,
                         float* __restrict__ v) {
    int idx = blockIdx.x * 256 + threadIdx.x;
    if (idx >= LAYERS * HEADS * HDIM) return;
    int i = idx / (HEADS * HDIM);
    int r = idx % (HEADS * HDIM);
    int h = r / HDIM, k = r % HDIM;
    float s = 0.f;
    #pragma unroll 4
    for (int o = 0; o < 32; ++o)
        s += att_edge[(i * HEADS + h) * 32 + o] *
             lin_edge_w[((size_t)i * HDIM + h * 32 + o) * HDIM + k];
    v[idx] = s;
}

__global__ void we_kernel(const float* __restrict__ v, const float* __restrict__ edge_emb_w,
                          const float* __restrict__ edge_emb_b, float* __restrict__ we,
                          float* __restrict__ be) {
    int idx = blockIdx.x * 256 + threadIdx.x;
    if (idx < LAYERS * HEADS * EDGE_F) {
        int i = idx / (HEADS * EDGE_F);
        int r = idx % (HEADS * EDGE_F);
        int h = r >> 5, f = r & 31;
        float s = 0.f;
        for (int k = 0; k < HDIM; ++k)
            s += v[(i * HEADS + h) * HDIM + k] * edge_emb_w[k * EDGE_F + f];
        we[idx] = s;
    } else if (idx < LAYERS * HEADS * EDGE_F + LAYERS * HEADS) {
        int j = idx - LAYERS * HEADS * EDGE_F;
        int i = j / HEADS, h = j % HEADS;
        float s = 0.f;
        for (int k = 0; k < HDIM; ++k) s += v[(i * HEADS + h) * HDIM + k] * edge_emb_b[k];
        be[j] = s;
    }
}

// ---------------------------------------------------------------- preE via MFMA
// preEb[idx][li*8+h] = ea_bf[idx,:] . we[li*8+h,:] + be[li*8+h]   ([NE][48] bf16)
// One wave = 16 edges, 3 x mfma_16x16x32 (48 output cols).
__global__ __launch_bounds__(256) void preE_kernel(const ushort* __restrict__ ea_bf,
                                                   const ushort* __restrict__ web,
                                                   const float* __restrict__ be,
                                                   ushort* __restrict__ preEb) {
    int wv = threadIdx.x >> 6, l = threadIdx.x & 63;
    int base = blockIdx.x * 64 + wv * 16;
    int m = l & 15, kq = (l >> 4) * 8;
    short8 afrag = *(const short8*)(ea_bf + (size_t)(base + m) * EDGE_F + kq);
    float4v zero = {0.f, 0.f, 0.f, 0.f};
    float4v acc[3];
    #pragma unroll
    for (int ct = 0; ct < 3; ++ct) {
        short8 bfrag = *(const short8*)(web + (size_t)(ct * 16 + m) * EDGE_F + kq);
        acc[ct] = __builtin_amdgcn_mfma_f32_16x16x32_bf16(afrag, bfrag, zero, 0, 0, 0);
    }
    // C/D: col = lane&15 (=m), row = (lane>>4)*4 + r
    #pragma unroll
    for (int ct = 0; ct < 3; ++ct) {
        int oc = ct * 16 + m;
        float bv = be[oc];
        #pragma unroll
        for (int r = 0; r < 4; ++r) {
            int row = (l >> 4) * 4 + r;
            preEb[(size_t)(base + row) * NOUT + oc] = f2bf(acc[ct][r] + bv);
        }
    }
}

// preL[l][n][h] = deg>0 ? mean over CSR range of preE (contains folded bias) : 0
__global__ __launch_bounds__(256) void preL_kernel(const ushort* __restrict__ preEb,
                                                   const int* __restrict__ row_ptr,
                                                   float* __restrict__ preL) {
    int g = threadIdx.x >> 5, c = threadIdx.x & 31;
    int n = blockIdx.x * 8 + g;  // NN % 8 == 0
    int start = row_ptr[n], end = row_ptr[n + 1];
    int deg = end - start;
    for (int li = 0; li < LAYERS; ++li) {
        const ushort* pb = preEb + li * 8;
        float s[8] = {};
        for (int idx = start + c; idx < end; idx += 32) {
            uint4 pk = *(const uint4*)(pb + (size_t)idx * NOUT);
            s[0] += bf2f((ushort)(pk.x & 0xffff)); s[1] += bf2f((ushort)(pk.x >> 16));
            s[2] += bf2f((ushort)(pk.y & 0xffff)); s[3] += bf2f((ushort)(pk.y >> 16));
            s[4] += bf2f((ushort)(pk.z & 0xffff)); s[5] += bf2f((ushort)(pk.z >> 16));
            s[6] += bf2f((ushort)(pk.w & 0xffff)); s[7] += bf2f((ushort)(pk.w >> 16));
        }
        #pragma unroll
        for (int off = 16; off >= 1; off >>= 1)
            #pragma unroll
            for (int h = 0; h < 8; ++h) s[h] += __shfl_xor(s[h], off, 32);
        if (c == 0) {
            float invd = deg > 0 ? 1.f / (float)deg : 0.f;
            float4* dstp = (float4*)(preL + ((size_t)li * NN + n) * 8);
            dstp[0] = make_float4(s[0] * invd, s[1] * invd, s[2] * invd, s[3] * invd);
            dstp[1] = make_float4(s[4] * invd, s[5] * invd, s[6] * invd, s[7] * invd);
        }
    }
}

// ---------------------------------------------------------------- splits
__global__ void split_kernel(const float* __restrict__ src, ushort* __restrict__ hi,
                             ushort* __restrict__ lo, int n) {
    int i = blockIdx.x * 256 + threadIdx.x;
    if (i >= n) return;
    float f = src[i];
    ushort h = f2bf(f);
    hi[i] = h;
    lo[i] = f2bf(f - bf2f(h));
}

__global__ void tobf_kernel(const float* __restrict__ src, ushort* __restrict__ dst, int n) {
    int i = blockIdx.x * 256 + threadIdx.x;
    if (i < n) dst[i] = f2bf(src[i]);
}

// ---------------------------------------------------------------- bf16x2 MFMA GEMM
__global__ __launch_bounds__(128) void gemm_bf2(const ushort* __restrict__ Ah,
                                                const ushort* __restrict__ Bh,
                                                const ushort* __restrict__ Bl,
                                                const float* __restrict__ bias,
                                                float* __restrict__ C,
                                                ushort* __restrict__ Chi,
                                                int N, int K, int J) {
    __shared__ ushort sAh[64][40], sBh[64][40], sBl[64][40];
    int nb = blockIdx.y * 64, jb = blockIdx.x * 64;
    int t = threadIdx.x, w = t >> 6, l = t & 63;
    int srow = t >> 1, sq = (t & 1) * 16;
    int fr = l & 15, fq = (l >> 4) * 8;
    float4v acc[2][4] = {};
    for (int kt = 0; kt < K; kt += 32) {
        int gr = nb + srow;
        short8 a0 = {0,0,0,0,0,0,0,0}, a1 = {0,0,0,0,0,0,0,0};
        if (gr < N) {
            const short8* pa = (const short8*)(Ah + (size_t)gr * K + kt + sq);
            a0 = pa[0]; a1 = pa[1];
        }
        *(short8*)&sAh[srow][sq] = a0; *(short8*)&sAh[srow][sq + 8] = a1;
        const short8* pb = (const short8*)(Bh + (size_t)(jb + srow) * K + kt + sq);
        short8 b0 = pb[0], b1 = pb[1];
        *(short8*)&sBh[srow][sq] = b0; *(short8*)&sBh[srow][sq + 8] = b1;
        const short8* pl = (const short8*)(Bl + (size_t)(jb + srow) * K + kt + sq);
        short8 l0 = pl[0], l1 = pl[1];
        *(short8*)&sBl[srow][sq] = l0; *(short8*)&sBl[srow][sq + 8] = l1;
        __syncthreads();
        short8 bh[4], bl[4];
        #pragma unroll
        for (int nt = 0; nt < 4; ++nt) {
            bh[nt] = *(const short8*)&sBh[nt * 16 + fr][fq];
            bl[nt] = *(const short8*)&sBl[nt * 16 + fr][fq];
        }
        #pragma unroll
        for (int mt = 0; mt < 2; ++mt) {
            short8 ah = *(const short8*)&sAh[w * 32 + mt * 16 + fr][fq];
            #pragma unroll
            for (int nt = 0; nt < 4; ++nt) {
                acc[mt][nt] = __builtin_amdgcn_mfma_f32_16x16x32_bf16(ah, bh[nt], acc[mt][nt], 0, 0, 0);
                acc[mt][nt] = __builtin_amdgcn_mfma_f32_16x16x32_bf16(ah, bl[nt], acc[mt][nt], 0, 0, 0);
            }
        }
        __syncthreads();
    }
    #pragma unroll
    for (int mt = 0; mt < 2; ++mt) {
        #pragma unroll
        for (int nt = 0; nt < 4; ++nt) {
            int col = jb + nt * 16 + fr;
            float bv = bias ? bias[col] : 0.f;
            #pragma unroll
            for (int r = 0; r < 4; ++r) {
                int row = nb + w * 32 + mt * 16 + (l >> 4) * 4 + r;
                if (row < N) {
                    float v = acc[mt][nt][r] + bv;
                    C[(size_t)row * J + col] = v;
                    if (Chi) Chi[(size_t)row * J + col] = f2bf(v);
                }
            }
        }
    }
}

// ---------------------------------------------------------------- per-node a_src/a_dst from bf16 xw
__global__ void asrcdst_kernel(const ushort* __restrict__ xwbf, const float* __restrict__ att_s,
                               const float* __restrict__ att_d, float* __restrict__ a_src,
                               float* __restrict__ a_dst) {
    int tid = blockIdx.x * 256 + threadIdx.x;
    if (tid >= NN * HEADS) return;
    int n = tid >> 3, h = tid & 7;
    const uint4* xv = (const uint4*)(xwbf + (size_t)n * HDIM + h * 32);
    const float4* sv = (const float4*)(att_s + h * 32);
    const float4* dv = (const float4*)(att_d + h * 32);
    float s1 = 0.f, s2 = 0.f;
    #pragma unroll
    for (int q = 0; q < 4; ++q) {
        uint4 pk = xv[q];
        float xx[8] = {bf2f((ushort)(pk.x & 0xffff)), bf2f((ushort)(pk.x >> 16)),
                       bf2f((ushort)(pk.y & 0xffff)), bf2f((ushort)(pk.y >> 16)),
                       bf2f((ushort)(pk.z & 0xffff)), bf2f((ushort)(pk.z >> 16)),
                       bf2f((ushort)(pk.w & 0xffff)), bf2f((ushort)(pk.w >> 16))};
        float4 a0 = sv[q * 2], a1 = sv[q * 2 + 1];
        float4 b0 = dv[q * 2], b1 = dv[q * 2 + 1];
        s1 += xx[0] * a0.x + xx[1] * a0.y + xx[2] * a0.z + xx[3] * a0.w
            + xx[4] * a1.x + xx[5] * a1.y + xx[6] * a1.z + xx[7] * a1.w;
        s2 += xx[0] * b0.x + xx[1] * b0.y + xx[2] * b0.z + xx[3] * b0.w
            + xx[4] * b1.x + xx[5] * b1.y + xx[6] * b1.z + xx[7] * b1.w;
    }
    a_src[tid] = s1;
    a_dst[tid] = s2;
}

__device__ __forceinline__ float gelu_exact(float x) {
    return 0.5f * x * (1.f + erff(x * 0.70710678118654752f));
}

// softmax without max-subtraction (shift-invariant; logits O(1), clamp guards overflow)
// pb = preEb + li*8 ; stride NOUT per edge slot
__device__ __forceinline__ float edge_wt_recompute(int idx, int sn, int hc, float adnh,
                                                   const ushort* __restrict__ pb,
                                                   const float* __restrict__ a_src) {
    float a = a_src[(size_t)sn * 8 + hc] + adnh + bf2f(pb[(size_t)idx * NOUT + hc]);
    a = a > 0.f ? a : 0.2f * a;
    return expf(fminf(a, 40.f));
}

// ---------------------------------------------------------------- fused alpha + softmax + aggregate + LN + GELU + residual
// NPB nodes/block, one wave per node (round-8 form; wave-coupling regressed twice).
__global__ __launch_bounds__(64 * NPB) void node_kernel(const float* __restrict__ xw,
                                                  const ushort* __restrict__ xwbf,
                                                  const ushort* __restrict__ pb,
                                                  const float* __restrict__ preL,
                                                  const float* __restrict__ a_src,
                                                  const float* __restrict__ a_dst,
                                                  const int* __restrict__ row_ptr,
                                                  const int* __restrict__ csr_src,
                                                  const float* __restrict__ h_prev,
                                                  float* __restrict__ h_next,
                                                  ushort* __restrict__ hhi,
                                                  const float* __restrict__ cb,
                                                  const float* __restrict__ lg,
                                                  const float* __restrict__ lb, int first) {
    __shared__ float lwAll[NPB][DCAP][9];
    int wv = threadIdx.x >> 6, l = threadIdx.x & 63;
    int n = blockIdx.x * NPB + wv;
    float (*lw)[9] = lwAll[wv];
    int start = row_ptr[n], end = row_ptr[n + 1];

    float adn[8], wl[8], s[8];
    #pragma unroll
    for (int h = 0; h < 8; ++h) adn[h] = a_dst[n * 8 + h];
    #pragma unroll
    for (int h = 0; h < 8; ++h) {
        float al = a_src[n * 8 + h] + adn[h] + preL[n * 8 + h];
        al = al > 0.f ? al : 0.2f * al;
        wl[h] = expf(fminf(al, 40.f));
        s[h] = (l == 0) ? wl[h] : 0.f;
    }
    // single pass: logits -> exp -> LDS cache + denom
    for (int idx = start + l; idx < end; idx += 64) {
        int sn = csr_src[idx];
        uint4 pk = *(const uint4*)(pb + (size_t)idx * NOUT);
        float p[8] = {bf2f((ushort)(pk.x & 0xffff)), bf2f((ushort)(pk.x >> 16)),
                      bf2f((ushort)(pk.y & 0xffff)), bf2f((ushort)(pk.y >> 16)),
                      bf2f((ushort)(pk.z & 0xffff)), bf2f((ushort)(pk.z >> 16)),
                      bf2f((ushort)(pk.w & 0xffff)), bf2f((ushort)(pk.w >> 16))};
        float4 s0 = *(const float4*)(a_src + (size_t)sn * 8);
        float4 s1 = *(const float4*)(a_src + (size_t)sn * 8 + 4);
        float al[8] = {s0.x + adn[0] + p[0], s0.y + adn[1] + p[1],
                       s0.z + adn[2] + p[2], s0.w + adn[3] + p[3],
                       s1.x + adn[4] + p[4], s1.y + adn[5] + p[5],
                       s1.z + adn[6] + p[6], s1.w + adn[7] + p[7]};
        int o = idx - start;
        #pragma unroll
        for (int h = 0; h < 8; ++h) {
            float a = al[h] > 0.f ? al[h] : 0.2f * al[h];
            float w = expf(fminf(a, 40.f));
            if (o < DCAP) lw[o][h] = w;
            s[h] += w;
        }
    }
    #pragma unroll
    for (int off = 32; off >= 1; off >>= 1)
        #pragma unroll
        for (int h = 0; h < 8; ++h) s[h] += __shfl_xor(s[h], off, 64);
    float inv[8];
    #pragma unroll
    for (int h = 0; h < 8; ++h) inv[h] = 1.f / (s[h] + 1e-16f);
    __syncthreads();  // lw visible

    // aggregate pass, unrolled x4 for gather ILP; lane owns channels 4l..4l+3, head hc=l>>3
    int hc = l >> 3;
    float adnh = adn[hc];
    const ushort* xb = xwbf + 4 * l;
    float acc[4];
    {
        float4 xs = *(const float4*)(xw + (size_t)n * HDIM + 4 * l);
        float wself = wl[hc];
        acc[0] = wself * xs.x; acc[1] = wself * xs.y;
        acc[2] = wself * xs.z; acc[3] = wself * xs.w;
    }
    int idx = start;
    for (; idx + 4 <= end; idx += 4) {
        int o = idx - start;
        int sn0 = csr_src[idx + 0], sn1 = csr_src[idx + 1];
        int sn2 = csr_src[idx + 2], sn3 = csr_src[idx + 3];
        uint2 g0 = *(const uint2*)(xb + (size_t)sn0 * HDIM);
        uint2 g1 = *(const uint2*)(xb + (size_t)sn1 * HDIM);
        uint2 g2 = *(const uint2*)(xb + (size_t)sn2 * HDIM);
        uint2 g3 = *(const uint2*)(xb + (size_t)sn3 * HDIM);
        float w0, w1, w2, w3;
        if (o + 4 <= DCAP) {
            w0 = lw[o][hc]; w1 = lw[o + 1][hc]; w2 = lw[o + 2][hc]; w3 = lw[o + 3][hc];
        } else {
            w0 = (o + 0 < DCAP) ? lw[o + 0][hc] : edge_wt_recompute(idx + 0, sn0, hc, adnh, pb, a_src);
            w1 = (o + 1 < DCAP) ? lw[o + 1][hc] : edge_wt_recompute(idx + 1, sn1, hc, adnh, pb, a_src);
            w2 = (o + 2 < DCAP) ? lw[o + 2][hc] : edge_wt_recompute(idx + 2, sn2, hc, adnh, pb, a_src);
            w3 = (o + 3 < DCAP) ? lw[o + 3][hc] : edge_wt_recompute(idx + 3, sn3, hc, adnh, pb, a_src);
        }
        acc[0] += w0 * bf2f((ushort)(g0.x & 0xffff)) + w1 * bf2f((ushort)(g1.x & 0xffff))
                + w2 * bf2f((ushort)(g2.x & 0xffff)) + w3 * bf2f((ushort)(g3.x & 0xffff));
        acc[1] += w0 * bf2f((ushort)(g0.x >> 16)) + w1 * bf2f((ushort)(g1.x >> 16))
                + w2 * bf2f((ushort)(g2.x >> 16)) + w3 * bf2f((ushort)(g3.x >> 16));
        acc[2] += w0 * bf2f((ushort)(g0.y & 0xffff)) + w1 * bf2f((ushort)(g1.y & 0xffff))
                + w2 * bf2f((ushort)(g2.y & 0xffff)) + w3 * bf2f((ushort)(g3.y & 0xffff));
        acc[3] += w0 * bf2f((ushort)(g0.y >> 16)) + w1 * bf2f((ushort)(g1.y >> 16))
                + w2 * bf2f((ushort)(g2.y >> 16)) + w3 * bf2f((ushort)(g3.y >> 16));
    }
    for (; idx < end; ++idx) {
        int o = idx - start;
        int sn = csr_src[idx];
        uint2 g = *(const uint2*)(xb + (size_t)sn * HDIM);
        float wt = (o < DCAP) ? lw[o][hc] : edge_wt_recompute(idx, sn, hc, adnh, pb, a_src);
        acc[0] += wt * bf2f((ushort)(g.x & 0xffff));
        acc[1] += wt * bf2f((ushort)(g.x >> 16));
        acc[2] += wt * bf2f((ushort)(g.y & 0xffff));
        acc[3] += wt * bf2f((ushort)(g.y >> 16));
    }
    float4 cb4 = *(const float4*)(cb + 4 * l);
    float invh = inv[hc];
    acc[0] = acc[0] * invh + cb4.x;
    acc[1] = acc[1] * invh + cb4.y;
    acc[2] = acc[2] * invh + cb4.z;
    acc[3] = acc[3] * invh + cb4.w;

    // LayerNorm over 256 channels
    float part = acc[0] + acc[1] + acc[2] + acc[3];
    #pragma unroll
    for (int off = 32; off >= 1; off >>= 1) part += __shfl_xor(part, off, 64);
    float mu = part * (1.f / 256.f);
    float p2 = 0.f;
    #pragma unroll
    for (int j = 0; j < 4; ++j) {
        float d = acc[j] - mu;
        p2 += d * d;
    }
    #pragma unroll
    for (int off = 32; off >= 1; off >>= 1) p2 += __shfl_xor(p2, off, 64);
    float rstd = rsqrtf(p2 * (1.f / 256.f) + 1e-5f);

    float4 lg4 = *(const float4*)(lg + 4 * l);
    float4 lb4 = *(const float4*)(lb + 4 * l);
    float o4[4];
    float lgv[4] = {lg4.x, lg4.y, lg4.z, lg4.w};
    float lbv[4] = {lb4.x, lb4.y, lb4.z, lb4.w};
    float4 hp = make_float4(0.f, 0.f, 0.f, 0.f);
    if (!first) hp = *(const float4*)(h_prev + (size_t)n * HDIM + 4 * l);
    float hpv[4] = {hp.x, hp.y, hp.z, hp.w};
    #pragma unroll
    for (int j = 0; j < 4; ++j) {
        float y = (acc[j] - mu) * rstd * lgv[j] + lbv[j];
        o4[j] = gelu_exact(y) + hpv[j];
    }
    *(float4*)(h_next + (size_t)n * HDIM + 4 * l) = make_float4(o4[0], o4[1], o4[2], o4[3]);
    uint2 ph;
    ph.x = (unsigned)f2bf(o4[0]) | ((unsigned)f2bf(o4[1]) << 16);
    ph.y = (unsigned)f2bf(o4[2]) | ((unsigned)f2bf(o4[3]) << 16);
    *(uint2*)(hhi + (size_t)n * HDIM + 4 * l) = ph;
}

// ---------------------------------------------------------------- graph readout
__global__ __launch_bounds__(256) void graph_sum_kernel(const float* __restrict__ h,
                                                        const int* __restrict__ batch,
                                                        float* __restrict__ sums) {
    int t = threadIdx.x;
    int n0 = blockIdx.x * 64;
    int n1 = min(NN, n0 + 64);
    float acc = 0.f;
    int cur = batch[n0];
    for (int n = n0; n < n1; ++n) {
        int b = batch[n];
        if (b != cur) {
            atomicAdd(&sums[cur * HDIM + t], acc);
            acc = 0.f;
            cur = b;
        }
        acc += h[(size_t)n * HDIM + t];
    }
    atomicAdd(&sums[cur * HDIM + t], acc);
}

__device__ __forceinline__ int lower_bound_dev(const int* a, int n, int v) {
    int lo = 0, hi = n;
    while (lo < hi) {
        int mid = (lo + hi) >> 1;
        if (a[mid] < v) lo = mid + 1; else hi = mid;
    }
    return lo;
}

// layer 1 of both MLP heads: grid (8, NG, 2)
__global__ __launch_bounds__(256) void mlp1_kernel(const float* __restrict__ sums,
                                                   const int* __restrict__ batch,
                                                   const float* __restrict__ pw1,
                                                   const float* __restrict__ pb1,
                                                   const float* __restrict__ mw1,
                                                   const float* __restrict__ mb1,
                                                   float* __restrict__ h1buf) {
    int slice = blockIdx.x, g = blockIdx.y, which = blockIdx.z;
    const float* w1 = which ? mw1 : pw1;
    const float* b1 = which ? mb1 : pb1;
    __shared__ float xg[512];
    __shared__ float cinv;
    int t = threadIdx.x;
    if (t == 0) {
        int s0 = lower_bound_dev(batch, NN, g), s1 = lower_bound_dev(batch, NN, g + 1);
        cinv = 1.f / fmaxf((float)(s1 - s0), 1.f);
    }
    __syncthreads();
    float sv = sums[g * HDIM + t];
    xg[t] = sv * cinv;
    xg[256 + t] = sv;
    __syncthreads();
    int row = slice * 32 + (t >> 3), lane8 = t & 7;
    const float* wr = w1 + (size_t)row * 512;
    float acc = 0.f;
    #pragma unroll
    for (int j = 0; j < 16; ++j) {
        int k = lane8 * 4 + j * 32;
        float4 wv = *(const float4*)(wr + k);
        acc += wv.x * xg[k] + wv.y * xg[k + 1] + wv.z * xg[k + 2] + wv.w * xg[k + 3];
    }
    #pragma unroll
    for (int off = 4; off >= 1; off >>= 1) acc += __shfl_xor(acc, off, 8);
    if (lane8 == 0) h1buf[((size_t)which * NG + g) * 256 + row] = gelu_exact(acc + b1[row]);
}

// layer 2: grid (4, NG, 2)
__global__ __launch_bounds__(256) void mlp2_kernel(const float* __restrict__ h1buf,
                                                   const float* __restrict__ pw2,
                                                   const float* __restrict__ pb2,
                                                   const float* __restrict__ mw2,
                                                   const float* __restrict__ mb2,
                                                   float* __restrict__ h2buf) {
    int slice = blockIdx.x, g = blockIdx.y, which = blockIdx.z;
    const float* w2 = which ? mw2 : pw2;
    const float* b2 = which ? mb2 : pb2;
    __shared__ float hx[256];
    int t = threadIdx.x;
    hx[t] = h1buf[((size_t)which * NG + g) * 256 + t];
    __syncthreads();
    int row = slice * 32 + (t >> 3), lane8 = t & 7;
    const float* wr = w2 + (size_t)row * 256;
    float acc = 0.f;
    #pragma unroll
    for (int j = 0; j < 8; ++j) {
        int k = lane8 * 4 + j * 32;
        float4 wv = *(const float4*)(wr + k);
        acc += wv.x * hx[k] + wv.y * hx[k + 1] + wv.z * hx[k + 2] + wv.w * hx[k + 3];
    }
    #pragma unroll
    for (int off = 4; off >= 1; off >>= 1) acc += __shfl_xor(acc, off, 8);
    if (lane8 == 0) h2buf[((size_t)which * NG + g) * 128 + row] = gelu_exact(acc + b2[row]);
}

// layer 3 + sigmoid: grid (NG, 2), 64 threads
__global__ __launch_bounds__(64) void mlp3_kernel(const float* __restrict__ h2buf,
                                                  const float* __restrict__ pw3,
                                                  const float* __restrict__ pb3,
                                                  const float* __restrict__ mw3,
                                                  const float* __restrict__ mb3,
                                                  float* __restrict__ out) {
    int g = blockIdx.x, which = blockIdx.y;
    const float* w3 = which ? mw3 : pw3;
    const float* b3 = which ? mb3 : pb3;
    int l = threadIdx.x;
    float v0 = h2buf[((size_t)which * NG + g) * 128 + l];
    float v1 = h2buf[((size_t)which * NG + g) * 128 + 64 + l];
    #pragma unroll
    for (int o = 0; o < 3; ++o) {
        float p = w3[o * 128 + l] * v0 + w3[o * 128 + 64 + l] * v1;
        #pragma unroll
        for (int off = 32; off >= 1; off >>= 1) p += __shfl_xor(p, off, 64);
        if (l == 0) out[which * (NG * 3) + g * 3 + o] = 1.f / (1.f + expf(-(p + b3[o])));
    }
}

// ---------------------------------------------------------------- launch
extern "C" void kernel_launch(void* const* d_in, const int* in_sizes, int n_in, void* d_out,
                              int out_size, void* d_ws, size_t ws_size, hipStream_t stream) {
    const float* x         = (const float*)d_in[0];
    const int*   ei        = (const int*)d_in[1];
    const int*   src       = ei;
    const int*   dst       = ei + NE;
    const float* edge_attr = (const float*)d_in[2];
    const int*   batch     = (const int*)d_in[3];
    const float* node_w    = (const float*)d_in[4];
    const float* node_b    = (const float*)d_in[5];
    const float* eew       = (const float*)d_in[6];
    const float* eeb       = (const float*)d_in[7];
    const float* lin_w     = (const float*)d_in[8];
    const float* att_src   = (const float*)d_in[9];
    const float* att_dst   = (const float*)d_in[10];
    const float* att_edge  = (const float*)d_in[11];
    const float* lin_edge_w= (const float*)d_in[12];
    const float* conv_b    = (const float*)d_in[13];
    const float* ln_g      = (const float*)d_in[14];
    const float* ln_b      = (const float*)d_in[15];
    const float* pw1 = (const float*)d_in[16]; const float* pb1 = (const float*)d_in[17];
    const float* pw2 = (const float*)d_in[18]; const float* pb2 = (const float*)d_in[19];
    const float* pw3 = (const float*)d_in[20]; const float* pb3 = (const float*)d_in[21];
    const float* mw1 = (const float*)d_in[22]; const float* mb1 = (const float*)d_in[23];
    const float* mw2 = (const float*)d_in[24]; const float* mb2 = (const float*)d_in[25];
    const float* mw3 = (const float*)d_in[26]; const float* mb3 = (const float*)d_in[27];
    float* out = (float*)d_out;

    float* wsf = (float*)d_ws;
    float* hA        = wsf; wsf += (size_t)NN * HDIM;
    float* hB        = wsf; wsf += (size_t)NN * HDIM;
    float* xw        = wsf; wsf += (size_t)NN * HDIM;
    float* preL      = wsf; wsf += (size_t)LAYERS * NN * 8;
    float* a_src     = wsf; wsf += (size_t)NN * HEADS;
    float* a_dst     = wsf; wsf += (size_t)NN * HEADS;
    float* vbuf      = wsf; wsf += (size_t)LAYERS * HEADS * HDIM;
    float* webuf     = wsf; wsf += (size_t)LAYERS * HEADS * EDGE_F;
    float* bebuf     = wsf; wsf += 64;
    float* sums      = wsf; wsf += (size_t)NG * HDIM;
    float* h1buf     = wsf; wsf += (size_t)2 * NG * 256;
    float* h2buf     = wsf; wsf += (size_t)2 * NG * 128;
    ushort* ubuf = (ushort*)wsf;
    ushort* ea_bf = ubuf; ubuf += (size_t)NE * EDGE_F;
    ushort* preEb = ubuf; ubuf += (size_t)NE * NOUT;
    ushort* webbf = ubuf; ubuf += (size_t)NOUT * EDGE_F;
    ushort* hhi  = ubuf; ubuf += (size_t)NN * HDIM;
    ushort* xwbf = ubuf; ubuf += (size_t)NN * HDIM;
    ushort* wbhi = ubuf; ubuf += (size_t)LAYERS * HDIM * HDIM;
    ushort* wblo = ubuf; ubuf += (size_t)LAYERS * HDIM * HDIM;
    ushort* xhi  = ubuf; ubuf += (size_t)NN * NODE_F;
    ushort* nwhi = ubuf; ubuf += (size_t)HDIM * NODE_F;
    ushort* nwlo = ubuf; ubuf += (size_t)HDIM * NODE_F;
    int* ibuf    = (int*)ubuf;
    int* cnt     = ibuf; ibuf += NN + 16;
    int* row_ptr = ibuf; ibuf += NN + 16;
    int* pos     = ibuf; ibuf += NN + 16;
    int* csr_src = ibuf; ibuf += NE;

    // CSR build (+ permute edge_attr to CSR order, bf16)
    hipMemsetAsync(cnt, 0, NN * sizeof(int), stream);
    count_kernel<<<(NE + 255) / 256, 256, 0, stream>>>(dst, cnt);
    scan_kernel<<<1, 1024, 0, stream>>>(cnt, row_ptr, pos);
    scatter_kernel<<<(NE + 255) / 256, 256, 0, stream>>>(src, dst, edge_attr, pos, csr_src,
                                                         ea_bf);

    // fold edge-attention weights; preE via MFMA; preL = mean over CSR range
    v_kernel<<<(LAYERS * HEADS * HDIM + 255) / 256, 256, 0, stream>>>(att_edge, lin_edge_w, vbuf);
    we_kernel<<<(LAYERS * HEADS * EDGE_F + LAYERS * HEADS + 255) / 256, 256, 0, stream>>>(
        vbuf, eew, eeb, webuf, bebuf);
    tobf_kernel<<<(NOUT * EDGE_F + 255) / 256, 256, 0, stream>>>(webuf, webbf, NOUT * EDGE_F);
    preE_kernel<<<NE / 64, 256, 0, stream>>>(ea_bf, webbf, bebuf, preEb);
    preL_kernel<<<NN / 8, 256, 0, stream>>>(preEb, row_ptr, preL);

    // GEMM operand prep: weights hi+lo, activations bf16-hi only
    split_kernel<<<((LAYERS * HDIM * HDIM) + 255) / 256, 256, 0, stream>>>(lin_w, wbhi, wblo,
                                                                           LAYERS * HDIM * HDIM);
    split_kernel<<<((HDIM * NODE_F) + 255) / 256, 256, 0, stream>>>(node_w, nwhi, nwlo,
                                                                    HDIM * NODE_F);
    tobf_kernel<<<((NN * NODE_F) + 255) / 256, 256, 0, stream>>>(x, xhi, NN * NODE_F);

    // node embedding: hA = x @ node_w.T + node_b  (+ bf16 of hA)
    {
        dim3 grid(HDIM / 64, (NN + 63) / 64);
        gemm_bf2<<<grid, 128, 0, stream>>>(xhi, nwhi, nwlo, node_b, hA, hhi, NN, NODE_F, HDIM);
    }

    float* cur = hA;
    float* nxt = hB;
    for (int i = 0; i < LAYERS; ++i) {
        dim3 grid(HDIM / 64, (NN + 63) / 64);
        gemm_bf2<<<grid, 128, 0, stream>>>(hhi, wbhi + (size_t)i * HDIM * HDIM,
                                           wblo + (size_t)i * HDIM * HDIM, nullptr, xw,
                                           xwbf, NN, HDIM, HDIM);
        asrcdst_kernel<<<(NN * HEADS + 255) / 256, 256, 0, stream>>>(
            xwbf, att_src + i * HEADS * 32, att_dst + i * HEADS * 32, a_src, a_dst);
        node_kernel<<<NN / NPB, 64 * NPB, 0, stream>>>(
            xw, xwbf, preEb + i * 8, preL + (size_t)i * NN * 8, a_src, a_dst,
            row_ptr, csr_src, cur, nxt, hhi, conv_b + i * HDIM, ln_g + i * HDIM,
            ln_b + i * HDIM, i == 0 ? 1 : 0);
        float* tmp = cur; cur = nxt; nxt = tmp;
    }

    hipMemsetAsync(sums, 0, NG * HDIM * sizeof(float), stream);
    graph_sum_kernel<<<(NN + 63) / 64, 256, 0, stream>>>(cur, batch, sums);
    {
        dim3 g1(8, NG, 2);
        mlp1_kernel<<<g1, 256, 0, stream>>>(sums, batch, pw1, pb1, mw1, mb1, h1buf);
        dim3 g2(4, NG, 2);
        mlp2_kernel<<<g2, 256, 0, stream>>>(h1buf, pw2, pb2, mw2, mb2, h2buf);
        dim3 g3(NG, 2);
        mlp3_kernel<<<g3, 64, 0, stream>>>(h2buf, pw3, pb3, mw3, mb3, out);
    }
}

// Round 11
// 610.078 us; speedup vs baseline: 1.1215x; 1.0088x over previous
//
#include <hip/hip_runtime.h>
#include <math.h>

#define NN 10000
#define NE 320000
#define NODE_F 64
#define EDGE_F 32
#define HDIM 256
#define HEADS 8
#define LAYERS 6
#define NG 16
#define NPB 2   // nodes per node_kernel block, ONE wave per node, no coupling
#define NOUT 48 // LAYERS*HEADS, interleaved preE layout [NE][48]

typedef __attribute__((ext_vector_type(8))) short short8;
typedef __attribute__((ext_vector_type(4))) float float4v;

// ---------------------------------------------------------------- CSR build
__global__ void count_kernel(const int* __restrict__ dst, int* __restrict__ cnt) {
    int e = blockIdx.x * 256 + threadIdx.x;
    if (e < NE) atomicAdd(&cnt[dst[e]], 1);
}

__global__ void scan_kernel(const int* __restrict__ cnt, int* __restrict__ row_ptr,
                            int* __restrict__ pos) {
    __shared__ int part[1024];
    int t = threadIdx.x;
    const int chunk = (NN + 1023) / 1024;  // 10
    int lo = t * chunk, hi = min(NN, lo + chunk);
    int s = 0;
    for (int i = lo; i < hi; ++i) s += cnt[i];
    part[t] = s;
    __syncthreads();
    for (int off = 1; off < 1024; off <<= 1) {
        int v = (t >= off) ? part[t - off] : 0;
        __syncthreads();
        part[t] += v;
        __syncthreads();
    }
    int base = (t == 0) ? 0 : part[t - 1];
    for (int i = lo; i < hi; ++i) {
        row_ptr[i] = base;
        pos[i] = base;
        base += cnt[i];
    }
    if (t == 1023) row_ptr[NN] = part[1023];
}

// ---------------------------------------------------------------- bf16 helpers
__device__ __forceinline__ ushort f2bf(float f) {
    union { float f; unsigned u; } v; v.f = f;
    unsigned u = v.u;
    return (ushort)((u + 0x7fffu + ((u >> 16) & 1u)) >> 16);
}
__device__ __forceinline__ float bf2f(ushort b) {
    union { unsigned u; float f; } v; v.u = ((unsigned)b) << 16; return v.f;
}

// scatter + permute edge_attr into CSR order as bf16 (64 B contiguous per edge)
__global__ void scatter_kernel(const int* __restrict__ src, const int* __restrict__ dst,
                               const float* __restrict__ edge_attr,
                               int* __restrict__ pos, int* __restrict__ csr_src,
                               ushort* __restrict__ ea_bf) {
    int e = blockIdx.x * 256 + threadIdx.x;
    if (e >= NE) return;
    int d = dst[e];
    int idx = atomicAdd(&pos[d], 1);
    csr_src[idx] = src[e];
    const float4* p = (const float4*)(edge_attr + (size_t)e * EDGE_F);
    uint4* q = (uint4*)(ea_bf + (size_t)idx * EDGE_F);
    #pragma unroll
    for (int i = 0; i < 4; ++i) {
        float4 v0 = p[i * 2], v1 = p[i * 2 + 1];
        uint4 pk;
        pk.x = (unsigned)f2bf(v0.x) | ((unsigned)f2bf(v0.y) << 16);
        pk.y = (unsigned)f2bf(v0.z) | ((unsigned)f2bf(v0.w) << 16);
        pk.z = (unsigned)f2bf(v1.x) | ((unsigned)f2bf(v1.y) << 16);
        pk.w = (unsigned)f2bf(v1.z) | ((unsigned)f2bf(v1.w) << 16);
        q[i] = pk;
    }
}

// ---------------------------------------------------------------- edge-attn weight folding
__global__ void v_kernel(const float* __restrict__ att_edge, const float* __restrict__ lin_edge_w,
                         float* __restrict__ v) {
    int idx = blockIdx.x * 256 + threadIdx.x;
    if (idx >= LAYERS * HEADS * HDIM) return;
    int i = idx / (HEADS * HDIM);
    int r = idx % (HEADS * HDIM);
    int h = r / HDIM, k = r % HDIM;
    float s = 0.f;
    #pragma unroll 4
    for (int o = 0; o < 32; ++o)
        s += att_edge[(i * HEADS + h) * 32 + o] *
             lin_edge_w[((size_t)i * HDIM + h * 32 + o) * HDIM + k];
    v[idx] = s;
}

__global__ void we_kernel(const float* __restrict__ v, const float* __restrict__ edge_emb_w,
                          const float* __restrict__ edge_emb_b, float* __restrict__ we,
                          float* __restrict__ be) {
    int idx = blockIdx.x * 256 + threadIdx.x;
    if (idx < LAYERS * HEADS * EDGE_F) {
        int i = idx / (HEADS * EDGE_F);
        int r = idx % (HEADS * EDGE_F);
        int h = r >> 5, f = r & 31;
        float s = 0.f;
        for (int k = 0; k < HDIM; ++k)
            s += v[(i * HEADS + h) * HDIM + k] * edge_emb_w[k * EDGE_F + f];
        we[idx] = s;
    } else if (idx < LAYERS * HEADS * EDGE_F + LAYERS * HEADS) {
        int j = idx - LAYERS * HEADS * EDGE_F;
        int i = j / HEADS, h = j % HEADS;
        float s = 0.f;
        for (int k = 0; k < HDIM; ++k) s += v[(i * HEADS + h) * HDIM + k] * edge_emb_b[k];
        be[j] = s;
    }
}

// ---------------------------------------------------------------- preE via MFMA
// preEb[idx][li*8+h] = ea_bf[idx,:] . we[li*8+h,:] + be[li*8+h]   ([NE][48] bf16)
__global__ __launch_bounds__(256) void preE_kernel(const ushort* __restrict__ ea_bf,
                                                   const ushort* __restrict__ web,
                                                   const float* __restrict__ be,
                                                   ushort* __restrict__ preEb) {
    int wv = threadIdx.x >> 6, l = threadIdx.x & 63;
    int base = blockIdx.x * 64 + wv * 16;
    int m = l & 15, kq = (l >> 4) * 8;
    short8 afrag = *(const short8*)(ea_bf + (size_t)(base + m) * EDGE_F + kq);
    float4v zero = {0.f, 0.f, 0.f, 0.f};
    float4v acc[3];
    #pragma unroll
    for (int ct = 0; ct < 3; ++ct) {
        short8 bfrag = *(const short8*)(web + (size_t)(ct * 16 + m) * EDGE_F + kq);
        acc[ct] = __builtin_amdgcn_mfma_f32_16x16x32_bf16(afrag, bfrag, zero, 0, 0, 0);
    }
    #pragma unroll
    for (int ct = 0; ct < 3; ++ct) {
        int oc = ct * 16 + m;
        float bv = be[oc];
        #pragma unroll
        for (int r = 0; r < 4; ++r) {
            int row = (l >> 4) * 4 + r;
            preEb[(size_t)(base + row) * NOUT + oc] = f2bf(acc[ct][r] + bv);
        }
    }
}

// preL[l][n][h] = deg>0 ? mean over CSR range of preE : 0 — full 96B row reads
__global__ __launch_bounds__(256) void preL_kernel(const ushort* __restrict__ preEb,
                                                   const int* __restrict__ row_ptr,
                                                   float* __restrict__ preL) {
    int g = threadIdx.x >> 5, c = threadIdx.x & 31;
    int n = blockIdx.x * 8 + g;  // NN % 8 == 0
    int start = row_ptr[n], end = row_ptr[n + 1];
    int deg = end - start;
    float s[NOUT] = {};
    for (int idx = start + c; idx < end; idx += 32) {
        const uint4* row = (const uint4*)(preEb + (size_t)idx * NOUT);
        #pragma unroll
        for (int q = 0; q < 6; ++q) {
            uint4 pk = row[q];
            s[q * 8 + 0] += bf2f((ushort)(pk.x & 0xffff));
            s[q * 8 + 1] += bf2f((ushort)(pk.x >> 16));
            s[q * 8 + 2] += bf2f((ushort)(pk.y & 0xffff));
            s[q * 8 + 3] += bf2f((ushort)(pk.y >> 16));
            s[q * 8 + 4] += bf2f((ushort)(pk.z & 0xffff));
            s[q * 8 + 5] += bf2f((ushort)(pk.z >> 16));
            s[q * 8 + 6] += bf2f((ushort)(pk.w & 0xffff));
            s[q * 8 + 7] += bf2f((ushort)(pk.w >> 16));
        }
    }
    #pragma unroll
    for (int off = 16; off >= 1; off >>= 1)
        #pragma unroll
        for (int h = 0; h < NOUT; ++h) s[h] += __shfl_xor(s[h], off, 32);
    if (c == 0) {
        float invd = deg > 0 ? 1.f / (float)deg : 0.f;
        for (int li = 0; li < LAYERS; ++li) {
            float4* dstp = (float4*)(preL + ((size_t)li * NN + n) * 8);
            dstp[0] = make_float4(s[li * 8 + 0] * invd, s[li * 8 + 1] * invd,
                                  s[li * 8 + 2] * invd, s[li * 8 + 3] * invd);
            dstp[1] = make_float4(s[li * 8 + 4] * invd, s[li * 8 + 5] * invd,
                                  s[li * 8 + 6] * invd, s[li * 8 + 7] * invd);
        }
    }
}

// ---------------------------------------------------------------- splits
__global__ void split_kernel(const float* __restrict__ src, ushort* __restrict__ hi,
                             ushort* __restrict__ lo, int n) {
    int i = blockIdx.x * 256 + threadIdx.x;
    if (i >= n) return;
    float f = src[i];
    ushort h = f2bf(f);
    hi[i] = h;
    lo[i] = f2bf(f - bf2f(h));
}

__global__ void tobf_kernel(const float* __restrict__ src, ushort* __restrict__ dst, int n) {
    int i = blockIdx.x * 256 + threadIdx.x;
    if (i < n) dst[i] = f2bf(src[i]);
}

// ---------------------------------------------------------------- bf16x2 MFMA GEMM
// C (f32) optional; Chi (bf16) optional.
__global__ __launch_bounds__(128) void gemm_bf2(const ushort* __restrict__ Ah,
                                                const ushort* __restrict__ Bh,
                                                const ushort* __restrict__ Bl,
                                                const float* __restrict__ bias,
                                                float* __restrict__ C,
                                                ushort* __restrict__ Chi,
                                                int N, int K, int J) {
    __shared__ ushort sAh[64][40], sBh[64][40], sBl[64][40];
    int nb = blockIdx.y * 64, jb = blockIdx.x * 64;
    int t = threadIdx.x, w = t >> 6, l = t & 63;
    int srow = t >> 1, sq = (t & 1) * 16;
    int fr = l & 15, fq = (l >> 4) * 8;
    float4v acc[2][4] = {};
    for (int kt = 0; kt < K; kt += 32) {
        int gr = nb + srow;
        short8 a0 = {0,0,0,0,0,0,0,0}, a1 = {0,0,0,0,0,0,0,0};
        if (gr < N) {
            const short8* pa = (const short8*)(Ah + (size_t)gr * K + kt + sq);
            a0 = pa[0]; a1 = pa[1];
        }
        *(short8*)&sAh[srow][sq] = a0; *(short8*)&sAh[srow][sq + 8] = a1;
        const short8* pb = (const short8*)(Bh + (size_t)(jb + srow) * K + kt + sq);
        short8 b0 = pb[0], b1 = pb[1];
        *(short8*)&sBh[srow][sq] = b0; *(short8*)&sBh[srow][sq + 8] = b1;
        const short8* pl = (const short8*)(Bl + (size_t)(jb + srow) * K + kt + sq);
        short8 l0 = pl[0], l1 = pl[1];
        *(short8*)&sBl[srow][sq] = l0; *(short8*)&sBl[srow][sq + 8] = l1;
        __syncthreads();
        short8 bh[4], bl[4];
        #pragma unroll
        for (int nt = 0; nt < 4; ++nt) {
            bh[nt] = *(const short8*)&sBh[nt * 16 + fr][fq];
            bl[nt] = *(const short8*)&sBl[nt * 16 + fr][fq];
        }
        #pragma unroll
        for (int mt = 0; mt < 2; ++mt) {
            short8 ah = *(const short8*)&sAh[w * 32 + mt * 16 + fr][fq];
            #pragma unroll
            for (int nt = 0; nt < 4; ++nt) {
                acc[mt][nt] = __builtin_amdgcn_mfma_f32_16x16x32_bf16(ah, bh[nt], acc[mt][nt], 0, 0, 0);
                acc[mt][nt] = __builtin_amdgcn_mfma_f32_16x16x32_bf16(ah, bl[nt], acc[mt][nt], 0, 0, 0);
            }
        }
        __syncthreads();
    }
    #pragma unroll
    for (int mt = 0; mt < 2; ++mt) {
        #pragma unroll
        for (int nt = 0; nt < 4; ++nt) {
            int col = jb + nt * 16 + fr;
            float bv = bias ? bias[col] : 0.f;
            #pragma unroll
            for (int r = 0; r < 4; ++r) {
                int row = nb + w * 32 + mt * 16 + (l >> 4) * 4 + r;
                if (row < N) {
                    float v = acc[mt][nt][r] + bv;
                    if (C) C[(size_t)row * J + col] = v;
                    if (Chi) Chi[(size_t)row * J + col] = f2bf(v);
                }
            }
        }
    }
}

// ---------------------------------------------------------------- per-node a_src/a_dst from bf16 xw
__global__ void asrcdst_kernel(const ushort* __restrict__ xwbf, const float* __restrict__ att_s,
                               const float* __restrict__ att_d, float* __restrict__ a_src,
                               float* __restrict__ a_dst) {
    int tid = blockIdx.x * 256 + threadIdx.x;
    if (tid >= NN * HEADS) return;
    int n = tid >> 3, h = tid & 7;
    const uint4* xv = (const uint4*)(xwbf + (size_t)n * HDIM + h * 32);
    const float4* sv = (const float4*)(att_s + h * 32);
    const float4* dv = (const float4*)(att_d + h * 32);
    float s1 = 0.f, s2 = 0.f;
    #pragma unroll
    for (int q = 0; q < 4; ++q) {
        uint4 pk = xv[q];
        float xx[8] = {bf2f((ushort)(pk.x & 0xffff)), bf2f((ushort)(pk.x >> 16)),
                       bf2f((ushort)(pk.y & 0xffff)), bf2f((ushort)(pk.y >> 16)),
                       bf2f((ushort)(pk.z & 0xffff)), bf2f((ushort)(pk.z >> 16)),
                       bf2f((ushort)(pk.w & 0xffff)), bf2f((ushort)(pk.w >> 16))};
        float4 a0 = sv[q * 2], a1 = sv[q * 2 + 1];
        float4 b0 = dv[q * 2], b1 = dv[q * 2 + 1];
        s1 += xx[0] * a0.x + xx[1] * a0.y + xx[2] * a0.z + xx[3] * a0.w
            + xx[4] * a1.x + xx[5] * a1.y + xx[6] * a1.z + xx[7] * a1.w;
        s2 += xx[0] * b0.x + xx[1] * b0.y + xx[2] * b0.z + xx[3] * b0.w
            + xx[4] * b1.x + xx[5] * b1.y + xx[6] * b1.z + xx[7] * b1.w;
    }
    a_src[tid] = s1;
    a_dst[tid] = s2;
}

__device__ __forceinline__ float gelu_exact(float x) {
    return 0.5f * x * (1.f + erff(x * 0.70710678118654752f));
}

// ---------------------------------------------------------------- fused single-pass node kernel
// No max-subtraction softmax -> each lane accumulates its own denominator redundantly:
// no LDS, no barriers, no cross-lane reduction for softmax. Lane owns channels
// 4l..4l+3 (all head hc = l>>3). One wave per node.
__global__ __launch_bounds__(64 * NPB) void node_kernel(const ushort* __restrict__ xwbf,
                                                  const ushort* __restrict__ pb,
                                                  const float* __restrict__ preL,
                                                  const float* __restrict__ a_src,
                                                  const float* __restrict__ a_dst,
                                                  const int* __restrict__ row_ptr,
                                                  const int* __restrict__ csr_src,
                                                  const float* __restrict__ h_prev,
                                                  float* __restrict__ h_next,
                                                  ushort* __restrict__ hhi,
                                                  const float* __restrict__ cb,
                                                  const float* __restrict__ lg,
                                                  const float* __restrict__ lb, int first) {
    int wv = threadIdx.x >> 6, l = threadIdx.x & 63;
    int n = blockIdx.x * NPB + wv;
    int start = row_ptr[n], end = row_ptr[n + 1];
    int hc = l >> 3;
    float adnh = a_dst[n * 8 + hc];
    const ushort* xb = xwbf + 4 * l;

    float den, acc[4];
    {
        float al = a_src[n * 8 + hc] + adnh + preL[n * 8 + hc];
        al = al > 0.f ? al : 0.2f * al;
        float wself = expf(fminf(al, 40.f));
        den = wself;
        uint2 gs = *(const uint2*)(xb + (size_t)n * HDIM);
        acc[0] = wself * bf2f((ushort)(gs.x & 0xffff));
        acc[1] = wself * bf2f((ushort)(gs.x >> 16));
        acc[2] = wself * bf2f((ushort)(gs.y & 0xffff));
        acc[3] = wself * bf2f((ushort)(gs.y >> 16));
    }
    int idx = start;
    for (; idx + 4 <= end; idx += 4) {
        int sn0 = csr_src[idx + 0], sn1 = csr_src[idx + 1];
        int sn2 = csr_src[idx + 2], sn3 = csr_src[idx + 3];
        uint2 g0 = *(const uint2*)(xb + (size_t)sn0 * HDIM);
        uint2 g1 = *(const uint2*)(xb + (size_t)sn1 * HDIM);
        uint2 g2 = *(const uint2*)(xb + (size_t)sn2 * HDIM);
        uint2 g3 = *(const uint2*)(xb + (size_t)sn3 * HDIM);
        float p0 = bf2f(pb[(size_t)(idx + 0) * NOUT + hc]);
        float p1 = bf2f(pb[(size_t)(idx + 1) * NOUT + hc]);
        float p2 = bf2f(pb[(size_t)(idx + 2) * NOUT + hc]);
        float p3 = bf2f(pb[(size_t)(idx + 3) * NOUT + hc]);
        float a0 = a_src[(size_t)sn0 * 8 + hc] + adnh + p0;
        float a1 = a_src[(size_t)sn1 * 8 + hc] + adnh + p1;
        float a2 = a_src[(size_t)sn2 * 8 + hc] + adnh + p2;
        float a3 = a_src[(size_t)sn3 * 8 + hc] + adnh + p3;
        a0 = a0 > 0.f ? a0 : 0.2f * a0;
        a1 = a1 > 0.f ? a1 : 0.2f * a1;
        a2 = a2 > 0.f ? a2 : 0.2f * a2;
        a3 = a3 > 0.f ? a3 : 0.2f * a3;
        float w0 = expf(fminf(a0, 40.f));
        float w1 = expf(fminf(a1, 40.f));
        float w2 = expf(fminf(a2, 40.f));
        float w3 = expf(fminf(a3, 40.f));
        den += (w0 + w1) + (w2 + w3);
        acc[0] += w0 * bf2f((ushort)(g0.x & 0xffff)) + w1 * bf2f((ushort)(g1.x & 0xffff))
                + w2 * bf2f((ushort)(g2.x & 0xffff)) + w3 * bf2f((ushort)(g3.x & 0xffff));
        acc[1] += w0 * bf2f((ushort)(g0.x >> 16)) + w1 * bf2f((ushort)(g1.x >> 16))
                + w2 * bf2f((ushort)(g2.x >> 16)) + w3 * bf2f((ushort)(g3.x >> 16));
        acc[2] += w0 * bf2f((ushort)(g0.y & 0xffff)) + w1 * bf2f((ushort)(g1.y & 0xffff))
                + w2 * bf2f((ushort)(g2.y & 0xffff)) + w3 * bf2f((ushort)(g3.y & 0xffff));
        acc[3] += w0 * bf2f((ushort)(g0.y >> 16)) + w1 * bf2f((ushort)(g1.y >> 16))
                + w2 * bf2f((ushort)(g2.y >> 16)) + w3 * bf2f((ushort)(g3.y >> 16));
    }
    for (; idx < end; ++idx) {
        int sn = csr_src[idx];
        uint2 g = *(const uint2*)(xb + (size_t)sn * HDIM);
        float a = a_src[(size_t)sn * 8 + hc] + adnh + bf2f(pb[(size_t)idx * NOUT + hc]);
        a = a > 0.f ? a : 0.2f * a;
        float wt = expf(fminf(a, 40.f));
        den += wt;
        acc[0] += wt * bf2f((ushort)(g.x & 0xffff));
        acc[1] += wt * bf2f((ushort)(g.x >> 16));
        acc[2] += wt * bf2f((ushort)(g.y & 0xffff));
        acc[3] += wt * bf2f((ushort)(g.y >> 16));
    }
    float4 cb4 = *(const float4*)(cb + 4 * l);
    float invh = 1.f / (den + 1e-16f);
    acc[0] = acc[0] * invh + cb4.x;
    acc[1] = acc[1] * invh + cb4.y;
    acc[2] = acc[2] * invh + cb4.z;
    acc[3] = acc[3] * invh + cb4.w;

    // LayerNorm over 256 channels
    float part = acc[0] + acc[1] + acc[2] + acc[3];
    #pragma unroll
    for (int off = 32; off >= 1; off >>= 1) part += __shfl_xor(part, off, 64);
    float mu = part * (1.f / 256.f);
    float p2 = 0.f;
    #pragma unroll
    for (int j = 0; j < 4; ++j) {
        float d = acc[j] - mu;
        p2 += d * d;
    }
    #pragma unroll
    for (int off = 32; off >= 1; off >>= 1) p2 += __shfl_xor(p2, off, 64);
    float rstd = rsqrtf(p2 * (1.f / 256.f) + 1e-5f);

    float4 lg4 = *(const float4*)(lg + 4 * l);
    float4 lb4 = *(const float4*)(lb + 4 * l);
    float o4[4];
    float lgv[4] = {lg4.x, lg4.y, lg4.z, lg4.w};
    float lbv[4] = {lb4.x, lb4.y, lb4.z, lb4.w};
    float4 hp = make_float4(0.f, 0.f, 0.f, 0.f);
    if (!first) hp = *(const float4*)(h_prev + (size_t)n * HDIM + 4 * l);
    float hpv[4] = {hp.x, hp.y, hp.z, hp.w};
    #pragma unroll
    for (int j = 0; j < 4; ++j) {
        float y = (acc[j] - mu) * rstd * lgv[j] + lbv[j];
        o4[j] = gelu_exact(y) + hpv[j];
    }
    *(float4*)(h_next + (size_t)n * HDIM + 4 * l) = make_float4(o4[0], o4[1], o4[2], o4[3]);
    uint2 ph;
    ph.x = (unsigned)f2bf(o4[0]) | ((unsigned)f2bf(o4[1]) << 16);
    ph.y = (unsigned)f2bf(o4[2]) | ((unsigned)f2bf(o4[3]) << 16);
    *(uint2*)(hhi + (size_t)n * HDIM + 4 * l) = ph;
}

// ---------------------------------------------------------------- graph readout
__global__ __launch_bounds__(256) void graph_sum_kernel(const float* __restrict__ h,
                                                        const int* __restrict__ batch,
                                                        float* __restrict__ sums) {
    int t = threadIdx.x;
    int n0 = blockIdx.x * 64;
    int n1 = min(NN, n0 + 64);
    float acc = 0.f;
    int cur = batch[n0];
    for (int n = n0; n < n1; ++n) {
        int b = batch[n];
        if (b != cur) {
            atomicAdd(&sums[cur * HDIM + t], acc);
            acc = 0.f;
            cur = b;
        }
        acc += h[(size_t)n * HDIM + t];
    }
    atomicAdd(&sums[cur * HDIM + t], acc);
}

__device__ __forceinline__ int lower_bound_dev(const int* a, int n, int v) {
    int lo = 0, hi = n;
    while (lo < hi) {
        int mid = (lo + hi) >> 1;
        if (a[mid] < v) lo = mid + 1; else hi = mid;
    }
    return lo;
}

// layer 1 of both MLP heads: grid (8, NG, 2)
__global__ __launch_bounds__(256) void mlp1_kernel(const float* __restrict__ sums,
                                                   const int* __restrict__ batch,
                                                   const float* __restrict__ pw1,
                                                   const float* __restrict__ pb1,
                                                   const float* __restrict__ mw1,
                                                   const float* __restrict__ mb1,
                                                   float* __restrict__ h1buf) {
    int slice = blockIdx.x, g = blockIdx.y, which = blockIdx.z;
    const float* w1 = which ? mw1 : pw1;
    const float* b1 = which ? mb1 : pb1;
    __shared__ float xg[512];
    __shared__ float cinv;
    int t = threadIdx.x;
    if (t == 0) {
        int s0 = lower_bound_dev(batch, NN, g), s1 = lower_bound_dev(batch, NN, g + 1);
        cinv = 1.f / fmaxf((float)(s1 - s0), 1.f);
    }
    __syncthreads();
    float sv = sums[g * HDIM + t];
    xg[t] = sv * cinv;
    xg[256 + t] = sv;
    __syncthreads();
    int row = slice * 32 + (t >> 3), lane8 = t & 7;
    const float* wr = w1 + (size_t)row * 512;
    float acc = 0.f;
    #pragma unroll
    for (int j = 0; j < 16; ++j) {
        int k = lane8 * 4 + j * 32;
        float4 wv = *(const float4*)(wr + k);
        acc += wv.x * xg[k] + wv.y * xg[k + 1] + wv.z * xg[k + 2] + wv.w * xg[k + 3];
    }
    #pragma unroll
    for (int off = 4; off >= 1; off >>= 1) acc += __shfl_xor(acc, off, 8);
    if (lane8 == 0) h1buf[((size_t)which * NG + g) * 256 + row] = gelu_exact(acc + b1[row]);
}

// layer 2: grid (4, NG, 2)
__global__ __launch_bounds__(256) void mlp2_kernel(const float* __restrict__ h1buf,
                                                   const float* __restrict__ pw2,
                                                   const float* __restrict__ pb2,
                                                   const float* __restrict__ mw2,
                                                   const float* __restrict__ mb2,
                                                   float* __restrict__ h2buf) {
    int slice = blockIdx.x, g = blockIdx.y, which = blockIdx.z;
    const float* w2 = which ? mw2 : pw2;
    const float* b2 = which ? mb2 : pb2;
    __shared__ float hx[256];
    int t = threadIdx.x;
    hx[t] = h1buf[((size_t)which * NG + g) * 256 + t];
    __syncthreads();
    int row = slice * 32 + (t >> 3), lane8 = t & 7;
    const float* wr = w2 + (size_t)row * 256;
    float acc = 0.f;
    #pragma unroll
    for (int j = 0; j < 8; ++j) {
        int k = lane8 * 4 + j * 32;
        float4 wv = *(const float4*)(wr + k);
        acc += wv.x * hx[k] + wv.y * hx[k + 1] + wv.z * hx[k + 2] + wv.w * hx[k + 3];
    }
    #pragma unroll
    for (int off = 4; off >= 1; off >>= 1) acc += __shfl_xor(acc, off, 8);
    if (lane8 == 0) h2buf[((size_t)which * NG + g) * 128 + row] = gelu_exact(acc + b2[row]);
}

// layer 3 + sigmoid: grid (NG, 2), 64 threads
__global__ __launch_bounds__(64) void mlp3_kernel(const float* __restrict__ h2buf,
                                                  const float* __restrict__ pw3,
                                                  const float* __restrict__ pb3,
                                                  const float* __restrict__ mw3,
                                                  const float* __restrict__ mb3,
                                                  float* __restrict__ out) {
    int g = blockIdx.x, which = blockIdx.y;
    const float* w3 = which ? mw3 : pw3;
    const float* b3 = which ? mb3 : pb3;
    int l = threadIdx.x;
    float v0 = h2buf[((size_t)which * NG + g) * 128 + l];
    float v1 = h2buf[((size_t)which * NG + g) * 128 + 64 + l];
    #pragma unroll
    for (int o = 0; o < 3; ++o) {
        float p = w3[o * 128 + l] * v0 + w3[o * 128 + 64 + l] * v1;
        #pragma unroll
        for (int off = 32; off >= 1; off >>= 1) p += __shfl_xor(p, off, 64);
        if (l == 0) out[which * (NG * 3) + g * 3 + o] = 1.f / (1.f + expf(-(p + b3[o])));
    }
}

// ---------------------------------------------------------------- launch
extern "C" void kernel_launch(void* const* d_in, const int* in_sizes, int n_in, void* d_out,
                              int out_size, void* d_ws, size_t ws_size, hipStream_t stream) {
    const float* x         = (const float*)d_in[0];
    const int*   ei        = (const int*)d_in[1];
    const int*   src       = ei;
    const int*   dst       = ei + NE;
    const float* edge_attr = (const float*)d_in[2];
    const int*   batch     = (const int*)d_in[3];
    const float* node_w    = (const float*)d_in[4];
    const float* node_b    = (const float*)d_in[5];
    const float* eew       = (const float*)d_in[6];
    const float* eeb       = (const float*)d_in[7];
    const float* lin_w     = (const float*)d_in[8];
    const float* att_src   = (const float*)d_in[9];
    const float* att_dst   = (const float*)d_in[10];
    const float* att_edge  = (const float*)d_in[11];
    const float* lin_edge_w= (const float*)d_in[12];
    const float* conv_b    = (const float*)d_in[13];
    const float* ln_g      = (const float*)d_in[14];
    const float* ln_b      = (const float*)d_in[15];
    const float* pw1 = (const float*)d_in[16]; const float* pb1 = (const float*)d_in[17];
    const float* pw2 = (const float*)d_in[18]; const float* pb2 = (const float*)d_in[19];
    const float* pw3 = (const float*)d_in[20]; const float* pb3 = (const float*)d_in[21];
    const float* mw1 = (const float*)d_in[22]; const float* mb1 = (const float*)d_in[23];
    const float* mw2 = (const float*)d_in[24]; const float* mb2 = (const float*)d_in[25];
    const float* mw3 = (const float*)d_in[26]; const float* mb3 = (const float*)d_in[27];
    float* out = (float*)d_out;

    float* wsf = (float*)d_ws;
    float* hA        = wsf; wsf += (size_t)NN * HDIM;
    float* hB        = wsf; wsf += (size_t)NN * HDIM;
    float* preL      = wsf; wsf += (size_t)LAYERS * NN * 8;
    float* a_src     = wsf; wsf += (size_t)NN * HEADS;
    float* a_dst     = wsf; wsf += (size_t)NN * HEADS;
    float* vbuf      = wsf; wsf += (size_t)LAYERS * HEADS * HDIM;
    float* webuf     = wsf; wsf += (size_t)LAYERS * HEADS * EDGE_F;
    float* bebuf     = wsf; wsf += 64;
    float* sums      = wsf; wsf += (size_t)NG * HDIM;
    float* h1buf     = wsf; wsf += (size_t)2 * NG * 256;
    float* h2buf     = wsf; wsf += (size_t)2 * NG * 128;
    ushort* ubuf = (ushort*)wsf;
    ushort* ea_bf = ubuf; ubuf += (size_t)NE * EDGE_F;
    ushort* preEb = ubuf; ubuf += (size_t)NE * NOUT;
    ushort* webbf = ubuf; ubuf += (size_t)NOUT * EDGE_F;
    ushort* hhi  = ubuf; ubuf += (size_t)NN * HDIM;
    ushort* xwbf = ubuf; ubuf += (size_t)NN * HDIM;
    ushort* wbhi = ubuf; ubuf += (size_t)LAYERS * HDIM * HDIM;
    ushort* wblo = ubuf; ubuf += (size_t)LAYERS * HDIM * HDIM;
    ushort* xhi  = ubuf; ubuf += (size_t)NN * NODE_F;
    ushort* nwhi = ubuf; ubuf += (size_t)HDIM * NODE_F;
    ushort* nwlo = ubuf; ubuf += (size_t)HDIM * NODE_F;
    int* ibuf    = (int*)ubuf;
    int* cnt     = ibuf; ibuf += NN + 16;
    int* row_ptr = ibuf; ibuf += NN + 16;
    int* pos     = ibuf; ibuf += NN + 16;
    int* csr_src = ibuf; ibuf += NE;

    // CSR build (+ permute edge_attr to CSR order, bf16)
    hipMemsetAsync(cnt, 0, NN * sizeof(int), stream);
    count_kernel<<<(NE + 255) / 256, 256, 0, stream>>>(dst, cnt);
    scan_kernel<<<1, 1024, 0, stream>>>(cnt, row_ptr, pos);
    scatter_kernel<<<(NE + 255) / 256, 256, 0, stream>>>(src, dst, edge_attr, pos, csr_src,
                                                         ea_bf);

    // fold edge-attention weights; preE via MFMA; preL = mean over CSR range
    v_kernel<<<(LAYERS * HEADS * HDIM + 255) / 256, 256, 0, stream>>>(att_edge, lin_edge_w, vbuf);
    we_kernel<<<(LAYERS * HEADS * EDGE_F + LAYERS * HEADS + 255) / 256, 256, 0, stream>>>(
        vbuf, eew, eeb, webuf, bebuf);
    tobf_kernel<<<(NOUT * EDGE_F + 255) / 256, 256, 0, stream>>>(webuf, webbf, NOUT * EDGE_F);
    preE_kernel<<<NE / 64, 256, 0, stream>>>(ea_bf, webbf, bebuf, preEb);
    preL_kernel<<<NN / 8, 256, 0, stream>>>(preEb, row_ptr, preL);

    // GEMM operand prep: weights hi+lo, activations bf16-hi only
    split_kernel<<<((LAYERS * HDIM * HDIM) + 255) / 256, 256, 0, stream>>>(lin_w, wbhi, wblo,
                                                                           LAYERS * HDIM * HDIM);
    split_kernel<<<((HDIM * NODE_F) + 255) / 256, 256, 0, stream>>>(node_w, nwhi, nwlo,
                                                                    HDIM * NODE_F);
    tobf_kernel<<<((NN * NODE_F) + 255) / 256, 256, 0, stream>>>(x, xhi, NN * NODE_F);

    // node embedding: hA = x @ node_w.T + node_b  (f32 + bf16)
    {
        dim3 grid(HDIM / 64, (NN + 63) / 64);
        gemm_bf2<<<grid, 128, 0, stream>>>(xhi, nwhi, nwlo, node_b, hA, hhi, NN, NODE_F, HDIM);
    }

    float* cur = hA;
    float* nxt = hB;
    for (int i = 0; i < LAYERS; ++i) {
        dim3 grid(HDIM / 64, (NN + 63) / 64);
        // layer GEMM writes ONLY bf16 xwbf (f32 xw eliminated)
        gemm_bf2<<<grid, 128, 0, stream>>>(hhi, wbhi + (size_t)i * HDIM * HDIM,
                                           wblo + (size_t)i * HDIM * HDIM, nullptr, nullptr,
                                           xwbf, NN, HDIM, HDIM);
        asrcdst_kernel<<<(NN * HEADS + 255) / 256, 256, 0, stream>>>(
            xwbf, att_src + i * HEADS * 32, att_dst + i * HEADS * 32, a_src, a_dst);
        node_kernel<<<NN / NPB, 64 * NPB, 0, stream>>>(
            xwbf, preEb + i * 8, preL + (size_t)i * NN * 8, a_src, a_dst,
            row_ptr, csr_src, cur, nxt, hhi, conv_b + i * HDIM, ln_g + i * HDIM,
            ln_b + i * HDIM, i == 0 ? 1 : 0);
        float* tmp = cur; cur = nxt; nxt = tmp;
    }

    hipMemsetAsync(sums, 0, NG * HDIM * sizeof(float), stream);
    graph_sum_kernel<<<(NN + 63) / 64, 256, 0, stream>>>(cur, batch, sums);
    {
        dim3 g1(8, NG, 2);
        mlp1_kernel<<<g1, 256, 0, stream>>>(sums, batch, pw1, pb1, mw1, mb1, h1buf);
        dim3 g2(4, NG, 2);
        mlp2_kernel<<<g2, 256, 0, stream>>>(h1buf, pw2, pb2, mw2, mb2, h2buf);
        dim3 g3(NG, 2);
        mlp3_kernel<<<g3, 64, 0, stream>>>(h2buf, pw3, pb3, mw3, mb3, out);
    }
}

// Round 12
// 606.201 us; speedup vs baseline: 1.1287x; 1.0064x over previous
//
#include <hip/hip_runtime.h>
#include <math.h>

#define NN 10000
#define NE 320000
#define NODE_F 64
#define EDGE_F 32
#define HDIM 256
#define HEADS 8
#define LAYERS 6
#define NG 16
#define NPB 2   // nodes per node_kernel block, ONE wave per node, no coupling
#define NOUT 48 // LAYERS*HEADS, interleaved preE layout [NE][48]

typedef __attribute__((ext_vector_type(8))) short short8;
typedef __attribute__((ext_vector_type(4))) float float4v;

// ---------------------------------------------------------------- CSR build
__global__ void count_kernel(const int* __restrict__ dst, int* __restrict__ cnt) {
    int e = blockIdx.x * 256 + threadIdx.x;
    if (e < NE) atomicAdd(&cnt[dst[e]], 1);
}

__global__ void scan_kernel(const int* __restrict__ cnt, int* __restrict__ row_ptr,
                            int* __restrict__ pos) {
    __shared__ int part[1024];
    int t = threadIdx.x;
    const int chunk = (NN + 1023) / 1024;  // 10
    int lo = t * chunk, hi = min(NN, lo + chunk);
    int s = 0;
    for (int i = lo; i < hi; ++i) s += cnt[i];
    part[t] = s;
    __syncthreads();
    for (int off = 1; off < 1024; off <<= 1) {
        int v = (t >= off) ? part[t - off] : 0;
        __syncthreads();
        part[t] += v;
        __syncthreads();
    }
    int base = (t == 0) ? 0 : part[t - 1];
    for (int i = lo; i < hi; ++i) {
        row_ptr[i] = base;
        pos[i] = base;
        base += cnt[i];
    }
    if (t == 1023) row_ptr[NN] = part[1023];
}

// ---------------------------------------------------------------- bf16 helpers
__device__ __forceinline__ ushort f2bf(float f) {
    union { float f; unsigned u; } v; v.f = f;
    unsigned u = v.u;
    return (ushort)((u + 0x7fffu + ((u >> 16) & 1u)) >> 16);
}
__device__ __forceinline__ float bf2f(ushort b) {
    union { unsigned u; float f; } v; v.u = ((unsigned)b) << 16; return v.f;
}

// scatter + permute edge_attr into CSR order as bf16 (64 B contiguous per edge)
__global__ void scatter_kernel(const int* __restrict__ src, const int* __restrict__ dst,
                               const float* __restrict__ edge_attr,
                               int* __restrict__ pos, int* __restrict__ csr_src,
                               ushort* __restrict__ ea_bf) {
    int e = blockIdx.x * 256 + threadIdx.x;
    if (e >= NE) return;
    int d = dst[e];
    int idx = atomicAdd(&pos[d], 1);
    csr_src[idx] = src[e];
    const float4* p = (const float4*)(edge_attr + (size_t)e * EDGE_F);
    uint4* q = (uint4*)(ea_bf + (size_t)idx * EDGE_F);
    #pragma unroll
    for (int i = 0; i < 4; ++i) {
        float4 v0 = p[i * 2], v1 = p[i * 2 + 1];
        uint4 pk;
        pk.x = (unsigned)f2bf(v0.x) | ((unsigned)f2bf(v0.y) << 16);
        pk.y = (unsigned)f2bf(v0.z) | ((unsigned)f2bf(v0.w) << 16);
        pk.z = (unsigned)f2bf(v1.x) | ((unsigned)f2bf(v1.y) << 16);
        pk.w = (unsigned)f2bf(v1.z) | ((unsigned)f2bf(v1.w) << 16);
        q[i] = pk;
    }
}

// ---------------------------------------------------------------- edge-attn weight folding
__global__ void v_kernel(const float* __restrict__ att_edge, const float* __restrict__ lin_edge_w,
                         float* __restrict__ v) {
    int idx = blockIdx.x * 256 + threadIdx.x;
    if (idx >= LAYERS * HEADS * HDIM) return;
    int i = idx / (HEADS * HDIM);
    int r = idx % (HEADS * HDIM);
    int h = r / HDIM, k = r % HDIM;
    float s = 0.f;
    #pragma unroll 4
    for (int o = 0; o < 32; ++o)
        s += att_edge[(i * HEADS + h) * 32 + o] *
             lin_edge_w[((size_t)i * HDIM + h * 32 + o) * HDIM + k];
    v[idx] = s;
}

__global__ void we_kernel(const float* __restrict__ v, const float* __restrict__ edge_emb_w,
                          const float* __restrict__ edge_emb_b, float* __restrict__ we,
                          float* __restrict__ be) {
    int idx = blockIdx.x * 256 + threadIdx.x;
    if (idx < LAYERS * HEADS * EDGE_F) {
        int i = idx / (HEADS * EDGE_F);
        int r = idx % (HEADS * EDGE_F);
        int h = r >> 5, f = r & 31;
        float s = 0.f;
        for (int k = 0; k < HDIM; ++k)
            s += v[(i * HEADS + h) * HDIM + k] * edge_emb_w[k * EDGE_F + f];
        we[idx] = s;
    } else if (idx < LAYERS * HEADS * EDGE_F + LAYERS * HEADS) {
        int j = idx - LAYERS * HEADS * EDGE_F;
        int i = j / HEADS, h = j % HEADS;
        float s = 0.f;
        for (int k = 0; k < HDIM; ++k) s += v[(i * HEADS + h) * HDIM + k] * edge_emb_b[k];
        be[j] = s;
    }
}

// ---------------------------------------------------------------- preE via MFMA
// preEb[idx][li*8+h] = ea_bf[idx,:] . we[li*8+h,:] + be[li*8+h]   ([NE][48] bf16)
__global__ __launch_bounds__(256) void preE_kernel(const ushort* __restrict__ ea_bf,
                                                   const ushort* __restrict__ web,
                                                   const float* __restrict__ be,
                                                   ushort* __restrict__ preEb) {
    int wv = threadIdx.x >> 6, l = threadIdx.x & 63;
    int base = blockIdx.x * 64 + wv * 16;
    int m = l & 15, kq = (l >> 4) * 8;
    short8 afrag = *(const short8*)(ea_bf + (size_t)(base + m) * EDGE_F + kq);
    float4v zero = {0.f, 0.f, 0.f, 0.f};
    float4v acc[3];
    #pragma unroll
    for (int ct = 0; ct < 3; ++ct) {
        short8 bfrag = *(const short8*)(web + (size_t)(ct * 16 + m) * EDGE_F + kq);
        acc[ct] = __builtin_amdgcn_mfma_f32_16x16x32_bf16(afrag, bfrag, zero, 0, 0, 0);
    }
    #pragma unroll
    for (int ct = 0; ct < 3; ++ct) {
        int oc = ct * 16 + m;
        float bv = be[oc];
        #pragma unroll
        for (int r = 0; r < 4; ++r) {
            int row = (l >> 4) * 4 + r;
            preEb[(size_t)(base + row) * NOUT + oc] = f2bf(acc[ct][r] + bv);
        }
    }
}

// preL[l][n][h] = deg>0 ? mean over CSR range of preE : 0 — full 96B row reads
__global__ __launch_bounds__(256) void preL_kernel(const ushort* __restrict__ preEb,
                                                   const int* __restrict__ row_ptr,
                                                   float* __restrict__ preL) {
    int g = threadIdx.x >> 5, c = threadIdx.x & 31;
    int n = blockIdx.x * 8 + g;  // NN % 8 == 0
    int start = row_ptr[n], end = row_ptr[n + 1];
    int deg = end - start;
    float s[NOUT] = {};
    for (int idx = start + c; idx < end; idx += 32) {
        const uint4* row = (const uint4*)(preEb + (size_t)idx * NOUT);
        #pragma unroll
        for (int q = 0; q < 6; ++q) {
            uint4 pk = row[q];
            s[q * 8 + 0] += bf2f((ushort)(pk.x & 0xffff));
            s[q * 8 + 1] += bf2f((ushort)(pk.x >> 16));
            s[q * 8 + 2] += bf2f((ushort)(pk.y & 0xffff));
            s[q * 8 + 3] += bf2f((ushort)(pk.y >> 16));
            s[q * 8 + 4] += bf2f((ushort)(pk.z & 0xffff));
            s[q * 8 + 5] += bf2f((ushort)(pk.z >> 16));
            s[q * 8 + 6] += bf2f((ushort)(pk.w & 0xffff));
            s[q * 8 + 7] += bf2f((ushort)(pk.w >> 16));
        }
    }
    #pragma unroll
    for (int off = 16; off >= 1; off >>= 1)
        #pragma unroll
        for (int h = 0; h < NOUT; ++h) s[h] += __shfl_xor(s[h], off, 32);
    if (c == 0) {
        float invd = deg > 0 ? 1.f / (float)deg : 0.f;
        for (int li = 0; li < LAYERS; ++li) {
            float4* dstp = (float4*)(preL + ((size_t)li * NN + n) * 8);
            dstp[0] = make_float4(s[li * 8 + 0] * invd, s[li * 8 + 1] * invd,
                                  s[li * 8 + 2] * invd, s[li * 8 + 3] * invd);
            dstp[1] = make_float4(s[li * 8 + 4] * invd, s[li * 8 + 5] * invd,
                                  s[li * 8 + 6] * invd, s[li * 8 + 7] * invd);
        }
    }
}

// ---------------------------------------------------------------- f32 -> bf16
__global__ void tobf_kernel(const float* __restrict__ src, ushort* __restrict__ dst, int n) {
    int i = blockIdx.x * 256 + threadIdx.x;
    if (i < n) dst[i] = f2bf(src[i]);
}

// ---------------------------------------------------------------- pure-bf16 MFMA GEMM
// C = A_bf . B_bf^T (+bias). Output is bf16 xwbf (already 2^-9 quantized), so the
// hi*lo correction term is below the output's own rounding floor -> dropped.
__global__ __launch_bounds__(128) void gemm_bf1(const ushort* __restrict__ Ah,
                                                const ushort* __restrict__ Bh,
                                                const float* __restrict__ bias,
                                                float* __restrict__ C,
                                                ushort* __restrict__ Chi,
                                                int N, int K, int J) {
    __shared__ ushort sAh[64][40], sBh[64][40];
    int nb = blockIdx.y * 64, jb = blockIdx.x * 64;
    int t = threadIdx.x, w = t >> 6, l = t & 63;
    int srow = t >> 1, sq = (t & 1) * 16;
    int fr = l & 15, fq = (l >> 4) * 8;
    float4v acc[2][4] = {};
    for (int kt = 0; kt < K; kt += 32) {
        int gr = nb + srow;
        short8 a0 = {0,0,0,0,0,0,0,0}, a1 = {0,0,0,0,0,0,0,0};
        if (gr < N) {
            const short8* pa = (const short8*)(Ah + (size_t)gr * K + kt + sq);
            a0 = pa[0]; a1 = pa[1];
        }
        *(short8*)&sAh[srow][sq] = a0; *(short8*)&sAh[srow][sq + 8] = a1;
        const short8* pb = (const short8*)(Bh + (size_t)(jb + srow) * K + kt + sq);
        short8 b0 = pb[0], b1 = pb[1];
        *(short8*)&sBh[srow][sq] = b0; *(short8*)&sBh[srow][sq + 8] = b1;
        __syncthreads();
        short8 bh[4];
        #pragma unroll
        for (int nt = 0; nt < 4; ++nt)
            bh[nt] = *(const short8*)&sBh[nt * 16 + fr][fq];
        #pragma unroll
        for (int mt = 0; mt < 2; ++mt) {
            short8 ah = *(const short8*)&sAh[w * 32 + mt * 16 + fr][fq];
            #pragma unroll
            for (int nt = 0; nt < 4; ++nt)
                acc[mt][nt] = __builtin_amdgcn_mfma_f32_16x16x32_bf16(ah, bh[nt], acc[mt][nt], 0, 0, 0);
        }
        __syncthreads();
    }
    #pragma unroll
    for (int mt = 0; mt < 2; ++mt) {
        #pragma unroll
        for (int nt = 0; nt < 4; ++nt) {
            int col = jb + nt * 16 + fr;
            float bv = bias ? bias[col] : 0.f;
            #pragma unroll
            for (int r = 0; r < 4; ++r) {
                int row = nb + w * 32 + mt * 16 + (l >> 4) * 4 + r;
                if (row < N) {
                    float v = acc[mt][nt][r] + bv;
                    if (C) C[(size_t)row * J + col] = v;
                    if (Chi) Chi[(size_t)row * J + col] = f2bf(v);
                }
            }
        }
    }
}

// ---------------------------------------------------------------- per-node a_src/a_dst from bf16 xw
__global__ void asrcdst_kernel(const ushort* __restrict__ xwbf, const float* __restrict__ att_s,
                               const float* __restrict__ att_d, float* __restrict__ a_src,
                               float* __restrict__ a_dst) {
    int tid = blockIdx.x * 256 + threadIdx.x;
    if (tid >= NN * HEADS) return;
    int n = tid >> 3, h = tid & 7;
    const uint4* xv = (const uint4*)(xwbf + (size_t)n * HDIM + h * 32);
    const float4* sv = (const float4*)(att_s + h * 32);
    const float4* dv = (const float4*)(att_d + h * 32);
    float s1 = 0.f, s2 = 0.f;
    #pragma unroll
    for (int q = 0; q < 4; ++q) {
        uint4 pk = xv[q];
        float xx[8] = {bf2f((ushort)(pk.x & 0xffff)), bf2f((ushort)(pk.x >> 16)),
                       bf2f((ushort)(pk.y & 0xffff)), bf2f((ushort)(pk.y >> 16)),
                       bf2f((ushort)(pk.z & 0xffff)), bf2f((ushort)(pk.z >> 16)),
                       bf2f((ushort)(pk.w & 0xffff)), bf2f((ushort)(pk.w >> 16))};
        float4 a0 = sv[q * 2], a1 = sv[q * 2 + 1];
        float4 b0 = dv[q * 2], b1 = dv[q * 2 + 1];
        s1 += xx[0] * a0.x + xx[1] * a0.y + xx[2] * a0.z + xx[3] * a0.w
            + xx[4] * a1.x + xx[5] * a1.y + xx[6] * a1.z + xx[7] * a1.w;
        s2 += xx[0] * b0.x + xx[1] * b0.y + xx[2] * b0.z + xx[3] * b0.w
            + xx[4] * b1.x + xx[5] * b1.y + xx[6] * b1.z + xx[7] * b1.w;
    }
    a_src[tid] = s1;
    a_dst[tid] = s2;
}

__device__ __forceinline__ float gelu_exact(float x) {
    return 0.5f * x * (1.f + erff(x * 0.70710678118654752f));
}

// ---------------------------------------------------------------- fused single-pass node kernel
// No-max softmax, per-lane redundant denominator, aggregate unrolled x8 for gather ILP.
__global__ __launch_bounds__(64 * NPB) void node_kernel(const ushort* __restrict__ xwbf,
                                                  const ushort* __restrict__ pb,
                                                  const float* __restrict__ preL,
                                                  const float* __restrict__ a_src,
                                                  const float* __restrict__ a_dst,
                                                  const int* __restrict__ row_ptr,
                                                  const int* __restrict__ csr_src,
                                                  const float* __restrict__ h_prev,
                                                  float* __restrict__ h_next,
                                                  ushort* __restrict__ hhi,
                                                  const float* __restrict__ cb,
                                                  const float* __restrict__ lg,
                                                  const float* __restrict__ lb, int first) {
    int wv = threadIdx.x >> 6, l = threadIdx.x & 63;
    int n = blockIdx.x * NPB + wv;
    int start = row_ptr[n], end = row_ptr[n + 1];
    int hc = l >> 3;
    float adnh = a_dst[n * 8 + hc];
    const ushort* xb = xwbf + 4 * l;

    float den, acc[4];
    {
        float al = a_src[n * 8 + hc] + adnh + preL[n * 8 + hc];
        al = al > 0.f ? al : 0.2f * al;
        float wself = expf(fminf(al, 40.f));
        den = wself;
        uint2 gs = *(const uint2*)(xb + (size_t)n * HDIM);
        acc[0] = wself * bf2f((ushort)(gs.x & 0xffff));
        acc[1] = wself * bf2f((ushort)(gs.x >> 16));
        acc[2] = wself * bf2f((ushort)(gs.y & 0xffff));
        acc[3] = wself * bf2f((ushort)(gs.y >> 16));
    }
    int idx = start;
    for (; idx + 8 <= end; idx += 8) {
        int sn[8];
        uint2 g[8];
        float p[8], a[8], w8[8];
        #pragma unroll
        for (int j = 0; j < 8; ++j) sn[j] = csr_src[idx + j];
        #pragma unroll
        for (int j = 0; j < 8; ++j) g[j] = *(const uint2*)(xb + (size_t)sn[j] * HDIM);
        #pragma unroll
        for (int j = 0; j < 8; ++j) p[j] = bf2f(pb[(size_t)(idx + j) * NOUT + hc]);
        #pragma unroll
        for (int j = 0; j < 8; ++j) a[j] = a_src[(size_t)sn[j] * 8 + hc] + adnh + p[j];
        #pragma unroll
        for (int j = 0; j < 8; ++j) {
            float t = a[j] > 0.f ? a[j] : 0.2f * a[j];
            w8[j] = expf(fminf(t, 40.f));
        }
        #pragma unroll
        for (int j = 0; j < 8; ++j) {
            den += w8[j];
            acc[0] += w8[j] * bf2f((ushort)(g[j].x & 0xffff));
            acc[1] += w8[j] * bf2f((ushort)(g[j].x >> 16));
            acc[2] += w8[j] * bf2f((ushort)(g[j].y & 0xffff));
            acc[3] += w8[j] * bf2f((ushort)(g[j].y >> 16));
        }
    }
    for (; idx < end; ++idx) {
        int sn = csr_src[idx];
        uint2 g = *(const uint2*)(xb + (size_t)sn * HDIM);
        float a = a_src[(size_t)sn * 8 + hc] + adnh + bf2f(pb[(size_t)idx * NOUT + hc]);
        a = a > 0.f ? a : 0.2f * a;
        float wt = expf(fminf(a, 40.f));
        den += wt;
        acc[0] += wt * bf2f((ushort)(g.x & 0xffff));
        acc[1] += wt * bf2f((ushort)(g.x >> 16));
        acc[2] += wt * bf2f((ushort)(g.y & 0xffff));
        acc[3] += wt * bf2f((ushort)(g.y >> 16));
    }
    float4 cb4 = *(const float4*)(cb + 4 * l);
    float invh = 1.f / (den + 1e-16f);
    acc[0] = acc[0] * invh + cb4.x;
    acc[1] = acc[1] * invh + cb4.y;
    acc[2] = acc[2] * invh + cb4.z;
    acc[3] = acc[3] * invh + cb4.w;

    // LayerNorm over 256 channels
    float part = acc[0] + acc[1] + acc[2] + acc[3];
    #pragma unroll
    for (int off = 32; off >= 1; off >>= 1) part += __shfl_xor(part, off, 64);
    float mu = part * (1.f / 256.f);
    float p2 = 0.f;
    #pragma unroll
    for (int j = 0; j < 4; ++j) {
        float d = acc[j] - mu;
        p2 += d * d;
    }
    #pragma unroll
    for (int off = 32; off >= 1; off >>= 1) p2 += __shfl_xor(p2, off, 64);
    float rstd = rsqrtf(p2 * (1.f / 256.f) + 1e-5f);

    float4 lg4 = *(const float4*)(lg + 4 * l);
    float4 lb4 = *(const float4*)(lb + 4 * l);
    float o4[4];
    float lgv[4] = {lg4.x, lg4.y, lg4.z, lg4.w};
    float lbv[4] = {lb4.x, lb4.y, lb4.z, lb4.w};
    float4 hp = make_float4(0.f, 0.f, 0.f, 0.f);
    if (!first) hp = *(const float4*)(h_prev + (size_t)n * HDIM + 4 * l);
    float hpv[4] = {hp.x, hp.y, hp.z, hp.w};
    #pragma unroll
    for (int j = 0; j < 4; ++j) {
        float y = (acc[j] - mu) * rstd * lgv[j] + lbv[j];
        o4[j] = gelu_exact(y) + hpv[j];
    }
    *(float4*)(h_next + (size_t)n * HDIM + 4 * l) = make_float4(o4[0], o4[1], o4[2], o4[3]);
    uint2 ph;
    ph.x = (unsigned)f2bf(o4[0]) | ((unsigned)f2bf(o4[1]) << 16);
    ph.y = (unsigned)f2bf(o4[2]) | ((unsigned)f2bf(o4[3]) << 16);
    *(uint2*)(hhi + (size_t)n * HDIM + 4 * l) = ph;
}

// ---------------------------------------------------------------- graph readout
__global__ __launch_bounds__(256) void graph_sum_kernel(const float* __restrict__ h,
                                                        const int* __restrict__ batch,
                                                        float* __restrict__ sums) {
    int t = threadIdx.x;
    int n0 = blockIdx.x * 64;
    int n1 = min(NN, n0 + 64);
    float acc = 0.f;
    int cur = batch[n0];
    for (int n = n0; n < n1; ++n) {
        int b = batch[n];
        if (b != cur) {
            atomicAdd(&sums[cur * HDIM + t], acc);
            acc = 0.f;
            cur = b;
        }
        acc += h[(size_t)n * HDIM + t];
    }
    atomicAdd(&sums[cur * HDIM + t], acc);
}

__device__ __forceinline__ int lower_bound_dev(const int* a, int n, int v) {
    int lo = 0, hi = n;
    while (lo < hi) {
        int mid = (lo + hi) >> 1;
        if (a[mid] < v) lo = mid + 1; else hi = mid;
    }
    return lo;
}

// layer 1 of both MLP heads: grid (8, NG, 2)
__global__ __launch_bounds__(256) void mlp1_kernel(const float* __restrict__ sums,
                                                   const int* __restrict__ batch,
                                                   const float* __restrict__ pw1,
                                                   const float* __restrict__ pb1,
                                                   const float* __restrict__ mw1,
                                                   const float* __restrict__ mb1,
                                                   float* __restrict__ h1buf) {
    int slice = blockIdx.x, g = blockIdx.y, which = blockIdx.z;
    const float* w1 = which ? mw1 : pw1;
    const float* b1 = which ? mb1 : pb1;
    __shared__ float xg[512];
    __shared__ float cinv;
    int t = threadIdx.x;
    if (t == 0) {
        int s0 = lower_bound_dev(batch, NN, g), s1 = lower_bound_dev(batch, NN, g + 1);
        cinv = 1.f / fmaxf((float)(s1 - s0), 1.f);
    }
    __syncthreads();
    float sv = sums[g * HDIM + t];
    xg[t] = sv * cinv;
    xg[256 + t] = sv;
    __syncthreads();
    int row = slice * 32 + (t >> 3), lane8 = t & 7;
    const float* wr = w1 + (size_t)row * 512;
    float acc = 0.f;
    #pragma unroll
    for (int j = 0; j < 16; ++j) {
        int k = lane8 * 4 + j * 32;
        float4 wv = *(const float4*)(wr + k);
        acc += wv.x * xg[k] + wv.y * xg[k + 1] + wv.z * xg[k + 2] + wv.w * xg[k + 3];
    }
    #pragma unroll
    for (int off = 4; off >= 1; off >>= 1) acc += __shfl_xor(acc, off, 8);
    if (lane8 == 0) h1buf[((size_t)which * NG + g) * 256 + row] = gelu_exact(acc + b1[row]);
}

// layer 2: grid (4, NG, 2)
__global__ __launch_bounds__(256) void mlp2_kernel(const float* __restrict__ h1buf,
                                                   const float* __restrict__ pw2,
                                                   const float* __restrict__ pb2,
                                                   const float* __restrict__ mw2,
                                                   const float* __restrict__ mb2,
                                                   float* __restrict__ h2buf) {
    int slice = blockIdx.x, g = blockIdx.y, which = blockIdx.z;
    const float* w2 = which ? mw2 : pw2;
    const float* b2 = which ? mb2 : pb2;
    __shared__ float hx[256];
    int t = threadIdx.x;
    hx[t] = h1buf[((size_t)which * NG + g) * 256 + t];
    __syncthreads();
    int row = slice * 32 + (t >> 3), lane8 = t & 7;
    const float* wr = w2 + (size_t)row * 256;
    float acc = 0.f;
    #pragma unroll
    for (int j = 0; j < 8; ++j) {
        int k = lane8 * 4 + j * 32;
        float4 wv = *(const float4*)(wr + k);
        acc += wv.x * hx[k] + wv.y * hx[k + 1] + wv.z * hx[k + 2] + wv.w * hx[k + 3];
    }
    #pragma unroll
    for (int off = 4; off >= 1; off >>= 1) acc += __shfl_xor(acc, off, 8);
    if (lane8 == 0) h2buf[((size_t)which * NG + g) * 128 + row] = gelu_exact(acc + b2[row]);
}

// layer 3 + sigmoid: grid (NG, 2), 64 threads
__global__ __launch_bounds__(64) void mlp3_kernel(const float* __restrict__ h2buf,
                                                  const float* __restrict__ pw3,
                                                  const float* __restrict__ pb3,
                                                  const float* __restrict__ mw3,
                                                  const float* __restrict__ mb3,
                                                  float* __restrict__ out) {
    int g = blockIdx.x, which = blockIdx.y;
    const float* w3 = which ? mw3 : pw3;
    const float* b3 = which ? mb3 : pb3;
    int l = threadIdx.x;
    float v0 = h2buf[((size_t)which * NG + g) * 128 + l];
    float v1 = h2buf[((size_t)which * NG + g) * 128 + 64 + l];
    #pragma unroll
    for (int o = 0; o < 3; ++o) {
        float p = w3[o * 128 + l] * v0 + w3[o * 128 + 64 + l] * v1;
        #pragma unroll
        for (int off = 32; off >= 1; off >>= 1) p += __shfl_xor(p, off, 64);
        if (l == 0) out[which * (NG * 3) + g * 3 + o] = 1.f / (1.f + expf(-(p + b3[o])));
    }
}

// ---------------------------------------------------------------- launch
extern "C" void kernel_launch(void* const* d_in, const int* in_sizes, int n_in, void* d_out,
                              int out_size, void* d_ws, size_t ws_size, hipStream_t stream) {
    const float* x         = (const float*)d_in[0];
    const int*   ei        = (const int*)d_in[1];
    const int*   src       = ei;
    const int*   dst       = ei + NE;
    const float* edge_attr = (const float*)d_in[2];
    const int*   batch     = (const int*)d_in[3];
    const float* node_w    = (const float*)d_in[4];
    const float* node_b    = (const float*)d_in[5];
    const float* eew       = (const float*)d_in[6];
    const float* eeb       = (const float*)d_in[7];
    const float* lin_w     = (const float*)d_in[8];
    const float* att_src   = (const float*)d_in[9];
    const float* att_dst   = (const float*)d_in[10];
    const float* att_edge  = (const float*)d_in[11];
    const float* lin_edge_w= (const float*)d_in[12];
    const float* conv_b    = (const float*)d_in[13];
    const float* ln_g      = (const float*)d_in[14];
    const float* ln_b      = (const float*)d_in[15];
    const float* pw1 = (const float*)d_in[16]; const float* pb1 = (const float*)d_in[17];
    const float* pw2 = (const float*)d_in[18]; const float* pb2 = (const float*)d_in[19];
    const float* pw3 = (const float*)d_in[20]; const float* pb3 = (const float*)d_in[21];
    const float* mw1 = (const float*)d_in[22]; const float* mb1 = (const float*)d_in[23];
    const float* mw2 = (const float*)d_in[24]; const float* mb2 = (const float*)d_in[25];
    const float* mw3 = (const float*)d_in[26]; const float* mb3 = (const float*)d_in[27];
    float* out = (float*)d_out;

    float* wsf = (float*)d_ws;
    float* hA        = wsf; wsf += (size_t)NN * HDIM;
    float* hB        = wsf; wsf += (size_t)NN * HDIM;
    float* preL      = wsf; wsf += (size_t)LAYERS * NN * 8;
    float* a_src     = wsf; wsf += (size_t)NN * HEADS;
    float* a_dst     = wsf; wsf += (size_t)NN * HEADS;
    float* vbuf      = wsf; wsf += (size_t)LAYERS * HEADS * HDIM;
    float* webuf     = wsf; wsf += (size_t)LAYERS * HEADS * EDGE_F;
    float* bebuf     = wsf; wsf += 64;
    float* sums      = wsf; wsf += (size_t)NG * HDIM;
    float* h1buf     = wsf; wsf += (size_t)2 * NG * 256;
    float* h2buf     = wsf; wsf += (size_t)2 * NG * 128;
    ushort* ubuf = (ushort*)wsf;
    ushort* ea_bf = ubuf; ubuf += (size_t)NE * EDGE_F;
    ushort* preEb = ubuf; ubuf += (size_t)NE * NOUT;
    ushort* webbf = ubuf; ubuf += (size_t)NOUT * EDGE_F;
    ushort* hhi  = ubuf; ubuf += (size_t)NN * HDIM;
    ushort* xwbf = ubuf; ubuf += (size_t)NN * HDIM;
    ushort* wbhi = ubuf; ubuf += (size_t)LAYERS * HDIM * HDIM;
    ushort* xhi  = ubuf; ubuf += (size_t)NN * NODE_F;
    ushort* nwhi = ubuf; ubuf += (size_t)HDIM * NODE_F;
    int* ibuf    = (int*)ubuf;
    int* cnt     = ibuf; ibuf += NN + 16;
    int* row_ptr = ibuf; ibuf += NN + 16;
    int* pos     = ibuf; ibuf += NN + 16;
    int* csr_src = ibuf; ibuf += NE;

    // CSR build (+ permute edge_attr to CSR order, bf16)
    hipMemsetAsync(cnt, 0, NN * sizeof(int), stream);
    count_kernel<<<(NE + 255) / 256, 256, 0, stream>>>(dst, cnt);
    scan_kernel<<<1, 1024, 0, stream>>>(cnt, row_ptr, pos);
    scatter_kernel<<<(NE + 255) / 256, 256, 0, stream>>>(src, dst, edge_attr, pos, csr_src,
                                                         ea_bf);

    // fold edge-attention weights; preE via MFMA; preL = mean over CSR range
    v_kernel<<<(LAYERS * HEADS * HDIM + 255) / 256, 256, 0, stream>>>(att_edge, lin_edge_w, vbuf);
    we_kernel<<<(LAYERS * HEADS * EDGE_F + LAYERS * HEADS + 255) / 256, 256, 0, stream>>>(
        vbuf, eew, eeb, webuf, bebuf);
    tobf_kernel<<<(NOUT * EDGE_F + 255) / 256, 256, 0, stream>>>(webuf, webbf, NOUT * EDGE_F);
    preE_kernel<<<NE / 64, 256, 0, stream>>>(ea_bf, webbf, bebuf, preEb);
    preL_kernel<<<NN / 8, 256, 0, stream>>>(preEb, row_ptr, preL);

    // GEMM operand prep: everything bf16 (pure-bf16 GEMM)
    tobf_kernel<<<((LAYERS * HDIM * HDIM) + 255) / 256, 256, 0, stream>>>(lin_w, wbhi,
                                                                          LAYERS * HDIM * HDIM);
    tobf_kernel<<<((HDIM * NODE_F) + 255) / 256, 256, 0, stream>>>(node_w, nwhi, HDIM * NODE_F);
    tobf_kernel<<<((NN * NODE_F) + 255) / 256, 256, 0, stream>>>(x, xhi, NN * NODE_F);

    // node embedding: hA = x @ node_w.T + node_b  (f32 + bf16)
    {
        dim3 grid(HDIM / 64, (NN + 63) / 64);
        gemm_bf1<<<grid, 128, 0, stream>>>(xhi, nwhi, node_b, hA, hhi, NN, NODE_F, HDIM);
    }

    float* cur = hA;
    float* nxt = hB;
    for (int i = 0; i < LAYERS; ++i) {
        dim3 grid(HDIM / 64, (NN + 63) / 64);
        // layer GEMM writes ONLY bf16 xwbf
        gemm_bf1<<<grid, 128, 0, stream>>>(hhi, wbhi + (size_t)i * HDIM * HDIM, nullptr,
                                           nullptr, xwbf, NN, HDIM, HDIM);
        asrcdst_kernel<<<(NN * HEADS + 255) / 256, 256, 0, stream>>>(
            xwbf, att_src + i * HEADS * 32, att_dst + i * HEADS * 32, a_src, a_dst);
        node_kernel<<<NN / NPB, 64 * NPB, 0, stream>>>(
            xwbf, preEb + i * 8, preL + (size_t)i * NN * 8, a_src, a_dst,
            row_ptr, csr_src, cur, nxt, hhi, conv_b + i * HDIM, ln_g + i * HDIM,
            ln_b + i * HDIM, i == 0 ? 1 : 0);
        float* tmp = cur; cur = nxt; nxt = tmp;
    }

    hipMemsetAsync(sums, 0, NG * HDIM * sizeof(float), stream);
    graph_sum_kernel<<<(NN + 63) / 64, 256, 0, stream>>>(cur, batch, sums);
    {
        dim3 g1(8, NG, 2);
        mlp1_kernel<<<g1, 256, 0, stream>>>(sums, batch, pw1, pb1, mw1, mb1, h1buf);
        dim3 g2(4, NG, 2);
        mlp2_kernel<<<g2, 256, 0, stream>>>(h1buf, pw2, pb2, mw2, mb2, h2buf);
        dim3 g3(NG, 2);
        mlp3_kernel<<<g3, 64, 0, stream>>>(h2buf, pw3, pb3, mw3, mb3, out);
    }
}